// Round 13
// baseline (366.545 us; speedup 1.0000x reference)
//
#include <hip/hip_runtime.h>
#include <hip/hip_bf16.h>
#include <math.h>

constexpr int Bb  = 64;    // batch
constexpr int Nn_ = 256;   // nodes
constexpr int Dd  = 1024;  // feature dim
constexpr int Hh  = 512;   // hidden
constexpr int NC  = 1000;  // classes
constexpr float LN_EPS = 1e-5f;

#define DEV __device__ __forceinline__

typedef unsigned short u16;
typedef __attribute__((ext_vector_type(8))) short bf16x8;   // 8 bf16 = 4 VGPR
typedef __attribute__((ext_vector_type(4))) float f32x4;
typedef __attribute__((ext_vector_type(4))) unsigned short u16x4;

// fast erf: Abramowitz-Stegun 7.1.26 (abs err < 1.5e-7) with HW rcp + HW exp.
DEV float erf_fast(float x) {
    const float ax = fabsf(x);
    const float t = __builtin_amdgcn_rcpf(fmaf(0.3275911f, ax, 1.0f));
    const float y = t * (0.254829592f + t * (-0.284496736f + t * (1.421413741f +
                    t * (-1.453152027f + t * 1.061405429f))));
    const float r = 1.0f - y * __expf(-ax * ax);
    return copysignf(r, x);
}
DEV float gelu_f(float x) { return 0.5f * x * (1.0f + erf_fast(x * 0.70710678118654752f)); }
DEV u16 bfb(float x) { __hip_bfloat16 h = __float2bfloat16(x); u16 u; __builtin_memcpy(&u, &h, 2); return u; }
DEV float fromb(u16 u) { unsigned int w = (unsigned int)u << 16; float f; __builtin_memcpy(&f, &w, 4); return f; }

// async global->LDS, 16B per lane
DEV void gload16(const void* g, void* l) {
    __builtin_amdgcn_global_load_lds(
        (const __attribute__((address_space(1))) void*)(uintptr_t)g,
        (__attribute__((address_space(3))) void*)(uintptr_t)l, 16, 0, 0);
}

// ---------------- bf16 MFMA GEMM: C = epi(A @ B), A [M,K] rm bf16, Bt [N,K] rm bf16 ----------------
// 128x128 tile, BK=32, 8 waves (2x4, per-wave 64x32), 16x16x32 MFMA, XOR slot-swizzle (rule #21).
// XCD-aware 1D grid (T1, A/B-proven round 11: -33 us).
enum { EP_BIAS_BF_CT = 0, EP_SBIAS_BF = 3 };

template<int EPI>
__global__ __launch_bounds__(512) void mgemm_k(
    const u16* __restrict__ Ag, const u16* __restrict__ Bg, void* __restrict__ Cg,
    const float* __restrict__ bias, const float* __restrict__ rsA,
    int M, int Nc, int K, long sA, long sB, long sC,
    int lognx, int logny, int lognz)
{
    __shared__ __align__(16) u16 sm[2][2][128 * 32];
    const int tid = threadIdx.x;
    const int l = tid & 63, w = tid >> 6;   // 8 waves
    const int wm = w >> 2, wn = w & 3;      // 2x4

    // XCD-aware decode (bijective; all dims are powers of 2)
    const int lid = blockIdx.x;
    const int xcd = lid & 7, idx = lid >> 3;
    int bxi, byi, z;
    if (lognz == 0) {                 // weight GEMM: group over x, spread y across XCDs
        bxi = idx & ((1 << lognx) - 1);
        byi = (xcd << (logny - 3)) | (idx >> lognx);
        z = 0;
    } else {                          // batched GEMM: group over (x,y), spread z across XCDs
        bxi = idx & ((1 << lognx) - 1);
        byi = (idx >> lognx) & ((1 << logny) - 1);
        z = (xcd << (lognz - 3)) | (idx >> (lognx + logny));
    }
    const int bm = byi * 128, bn = bxi * 128;

    const u16* Ab  = Ag + (long)z * sA;
    const u16* Bbp = Bg + (long)z * sB;

    f32x4 acc[4][2] = {};
    const int nt = K >> 5;

    auto stage = [&](int db, int t) {
        const long kk = (long)t << 5;
        const int o = tid * 16;                         // 512 lanes x 16B = full 8KB operand tile
        const int r = o >> 6;                           // tile row 0..127
        const int g = ((o >> 4) & 3) ^ ((r >> 1) & 3);  // inverse-swizzled k-slot
        gload16(Ab  + (long)(bm + r) * K + kk + g * 8, (char*)&sm[db][0][0] + o);
        gload16(Bbp + (long)(bn + r) * K + kk + g * 8, (char*)&sm[db][1][0] + o);
    };

    stage(0, 0);
    __syncthreads();
    for (int t = 0; t < nt; ++t) {
        const int db = t & 1;
        if (t + 1 < nt) stage(db ^ 1, t + 1);
        const int lr = l & 15, g = l >> 4;
        bf16x8 af[4], bfr[2];
        #pragma unroll
        for (int fm = 0; fm < 4; ++fm) {
            const int r = wm * 64 + fm * 16 + lr;
            af[fm] = *(const bf16x8*)((const char*)&sm[db][0][0] + r * 64 + ((g ^ ((r >> 1) & 3)) << 4));
        }
        #pragma unroll
        for (int fn = 0; fn < 2; ++fn) {
            const int r = wn * 32 + fn * 16 + lr;
            bfr[fn] = *(const bf16x8*)((const char*)&sm[db][1][0] + r * 64 + ((g ^ ((r >> 1) & 3)) << 4));
        }
        #pragma unroll
        for (int fm = 0; fm < 4; ++fm)
            #pragma unroll
            for (int fn = 0; fn < 2; ++fn)
                acc[fm][fn] = __builtin_amdgcn_mfma_f32_16x16x32_bf16(af[fm], bfr[fn], acc[fm][fn], 0, 0, 0);
        __syncthreads();
    }

    // epilogue: C/D layout col=lane&15, row=(lane>>4)*4+reg (m89-verified)
    const int lr = l & 15, lg = l >> 4;
    if constexpr (EPI == EP_SBIAS_BF) {
        u16* Cb = (u16*)Cg;
        #pragma unroll
        for (int fm = 0; fm < 4; ++fm)
            #pragma unroll
            for (int fn = 0; fn < 2; ++fn) {
                const int gc = bn + wn * 32 + fn * 16 + lr;
                const float bv = bias[gc];
                #pragma unroll
                for (int rg = 0; rg < 4; ++rg) {
                    const int gm = bm + wm * 64 + fm * 16 + lg * 4 + rg;
                    Cb[(long)gm * Nc + gc] = bfb(acc[fm][fn][rg] + rsA[gm] * bv);
                }
            }
    } else {  // EP_BIAS_BF_CT: transposed store out[gm>>8][gc][gm&255]
        #pragma unroll
        for (int fm = 0; fm < 4; ++fm) {
            const int gm0 = bm + wm * 64 + fm * 16 + lg * 4;
            #pragma unroll
            for (int fn = 0; fn < 2; ++fn) {
                const int gc = bn + wn * 32 + fn * 16 + lr;
                const float bv = bias[gc];
                u16x4 vals;
                #pragma unroll
                for (int rg = 0; rg < 4; ++rg) vals[rg] = bfb(acc[fm][fn][rg] + bv);
                const long addr = (long)(gm0 >> 8) * ((long)Nc * 256) + (long)gc * 256 + (gm0 & 255);
                *(u16x4*)&((u16*)Cg)[addr] = vals;
            }
        }
    }
}

// ---------------- fused graph double-multiply: AZ = Ahat @ gelu(Ahat @ Y1), column-sliced ----------------
// One block per (batch z, 128-col slice cs of Hh). A-fragments loaded PER KS-STEP from global
// (L2-resident, XCD-grouped) -- round-12's af[4][8] preload forced spills at the 128-VGPR cap (rule #20).
// Z1 slice lives only in LDS (kills the 33.5MB/iter Z1t global round-trip).
// LDS: sY [128 c][256 k] u16 XOR-swizzled (rule #21), sZ [128 c][256 r] swizzled transpose-store. 128KB.
__global__ __launch_bounds__(512) void ayy_k(
    const u16* __restrict__ Ahat, const u16* __restrict__ Y1t, u16* __restrict__ AZ)
{
    __shared__ __align__(16) u16 sY[128 * 256];
    __shared__ __align__(16) u16 sZ[128 * 256];

    const int tid = threadIdx.x;
    const int l = tid & 63, w = tid >> 6;
    const int wm = w >> 1, wn = w & 1;

    const int lid = blockIdx.x;                 // 256 blocks; all 4 slices of a batch on one XCD
    const int xcd = lid & 7, idx = lid >> 3;
    const int cs = idx & 3;
    const int z  = xcd * 8 + (idx >> 2);

    const u16* Ab = Ahat + (long)z * Nn_ * Nn_;
    const u16* Yb = Y1t + (long)z * Hh * Nn_ + (long)(cs * 128) * Nn_;  // [128 c][256 k]

    // stage Y1 slice -> sY, swizzle byte ^= ((c&7)<<4) applied via pre-swizzled SOURCE
    #pragma unroll
    for (int i = 0; i < 8; ++i) {
        const int o = i * 8192 + tid * 16;      // linear LDS byte offset
        const int c = o >> 9;
        const int wb = (o & 511) ^ ((c & 7) << 4);
        gload16((const char*)Yb + (long)c * 512 + wb, (char*)sY + o);
    }

    const int lr = l & 15, g = l >> 4;
    __syncthreads();

    // ---- mult1: Z1 = gelu(A @ Y1slice) ----
    f32x4 acc[4][4] = {};
    #pragma unroll
    for (int ks = 0; ks < 8; ++ks) {
        bf16x8 af[4], bfr[4];
        #pragma unroll
        for (int fm = 0; fm < 4; ++fm) {
            const int r = wm * 64 + fm * 16 + lr;
            af[fm] = *(const bf16x8*)(Ab + (long)r * Nn_ + ks * 32 + g * 8);
        }
        #pragma unroll
        for (int fn = 0; fn < 4; ++fn) {
            const int c = wn * 64 + fn * 16 + lr;
            const int kb = (ks * 64 + g * 16) ^ ((c & 7) << 4);
            bfr[fn] = *(const bf16x8*)((const char*)sY + c * 512 + kb);
        }
        #pragma unroll
        for (int fm = 0; fm < 4; ++fm)
            #pragma unroll
            for (int fn = 0; fn < 4; ++fn)
                acc[fm][fn] = __builtin_amdgcn_mfma_f32_16x16x32_bf16(af[fm], bfr[fn], acc[fm][fn], 0, 0, 0);
    }
    // gelu + pack + swizzled transpose-store into sZ[c][r]: byte = c*512 + ((r*2) ^ ((c&7)<<4))
    #pragma unroll
    for (int fm = 0; fm < 4; ++fm)
        #pragma unroll
        for (int fn = 0; fn < 4; ++fn) {
            const int c = wn * 64 + fn * 16 + lr;
            const int r0 = wm * 64 + fm * 16 + g * 4;
            u16x4 v;
            #pragma unroll
            for (int rg = 0; rg < 4; ++rg) v[rg] = bfb(gelu_f(acc[fm][fn][rg]));
            *(u16x4*)((char*)sZ + c * 512 + ((r0 * 2) ^ ((c & 7) << 4))) = v;
            acc[fm][fn] = f32x4{0.f, 0.f, 0.f, 0.f};   // reset in place for mult2
        }
    __syncthreads();

    // ---- mult2: AZ = A @ Z1  (A re-read from L2; k runs over rows r of Z1) ----
    #pragma unroll
    for (int ks = 0; ks < 8; ++ks) {
        bf16x8 af[4], bfr[4];
        #pragma unroll
        for (int fm = 0; fm < 4; ++fm) {
            const int r = wm * 64 + fm * 16 + lr;
            af[fm] = *(const bf16x8*)(Ab + (long)r * Nn_ + ks * 32 + g * 8);
        }
        #pragma unroll
        for (int fn = 0; fn < 4; ++fn) {
            const int c = wn * 64 + fn * 16 + lr;
            const int kb = (ks * 64 + g * 16) ^ ((c & 7) << 4);
            bfr[fn] = *(const bf16x8*)((const char*)sZ + c * 512 + kb);
        }
        #pragma unroll
        for (int fm = 0; fm < 4; ++fm)
            #pragma unroll
            for (int fn = 0; fn < 4; ++fn)
                acc[fm][fn] = __builtin_amdgcn_mfma_f32_16x16x32_bf16(af[fm], bfr[fn], acc[fm][fn], 0, 0, 0);
    }
    // write AZ row-major [b][256][512]
    u16* Ob = AZ + (long)z * Nn_ * Hh + cs * 128;
    #pragma unroll
    for (int fm = 0; fm < 4; ++fm)
        #pragma unroll
        for (int fn = 0; fn < 4; ++fn)
            #pragma unroll
            for (int rg = 0; rg < 4; ++rg) {
                const int r = wm * 64 + fm * 16 + g * 4 + rg;
                const int c = wn * 64 + fn * 16 + lr;
                Ob[(long)r * Hh + c] = bfb(acc[fm][fn][rg]);
            }
}

// ---------------- d2 gram via split-bf16 (hi*hi + hi*lo + lo*hi), symmetric-triangle + XCD swizzle ----
__global__ __launch_bounds__(512) void d2mm_k(
    const u16* __restrict__ HL, const float* __restrict__ sq, float* __restrict__ d2)
{
    __shared__ __align__(16) u16 sm[2][4][128 * 32];  // [dbuf][Ahi,Alo,Bhi,Blo]
    const int tid = threadIdx.x;
    const int l = tid & 63, w = tid >> 6;     // 8 waves
    const int wm = w >> 2, wn = w & 3;        // 2x4

    const int lid = blockIdx.x;            // 0..191
    const int xcd = lid & 7, q = lid >> 3; // q 0..23
    const int j   = q % 3;                 // triangle tile: 0=(0,0) 1=(0,128) 2=(128,128)
    const int z   = (q / 3) * 8 + xcd;     // batch, bijective over [0,64)
    const int bm  = (j == 2) ? 128 : 0;
    const int bn  = (j == 0) ? 0 : 128;

    const u16* Hb = HL + (long)z * Nn_ * 2048;

    f32x4 acc[4][2] = {};

    auto stage = [&](int db, int t) {
        const long kk = (long)t << 5;
        const int o = tid * 16;
        const int r = o >> 6;
        const int g = ((o >> 4) & 3) ^ ((r >> 1) & 3);
        const long ka = kk + g * 8;
        gload16(Hb + (long)(bm + r) * 2048 + ka,        (char*)&sm[db][0][0] + o);
        gload16(Hb + (long)(bm + r) * 2048 + 1024 + ka, (char*)&sm[db][1][0] + o);
        gload16(Hb + (long)(bn + r) * 2048 + ka,        (char*)&sm[db][2][0] + o);
        gload16(Hb + (long)(bn + r) * 2048 + 1024 + ka, (char*)&sm[db][3][0] + o);
    };

    stage(0, 0);
    __syncthreads();
    for (int t = 0; t < 32; ++t) {
        const int db = t & 1;
        if (t + 1 < 32) stage(db ^ 1, t + 1);
        const int lr = l & 15, g = l >> 4;
        bf16x8 ah[4], al[4], bh[2], bl[2];
        #pragma unroll
        for (int fm = 0; fm < 4; ++fm) {
            const int r = wm * 64 + fm * 16 + lr;
            const int off = r * 64 + ((g ^ ((r >> 1) & 3)) << 4);
            ah[fm] = *(const bf16x8*)((const char*)&sm[db][0][0] + off);
            al[fm] = *(const bf16x8*)((const char*)&sm[db][1][0] + off);
        }
        #pragma unroll
        for (int fn = 0; fn < 2; ++fn) {
            const int r = wn * 32 + fn * 16 + lr;
            const int off = r * 64 + ((g ^ ((r >> 1) & 3)) << 4);
            bh[fn] = *(const bf16x8*)((const char*)&sm[db][2][0] + off);
            bl[fn] = *(const bf16x8*)((const char*)&sm[db][3][0] + off);
        }
        #pragma unroll
        for (int fm = 0; fm < 4; ++fm)
            #pragma unroll
            for (int fn = 0; fn < 2; ++fn) {
                acc[fm][fn] = __builtin_amdgcn_mfma_f32_16x16x32_bf16(ah[fm], bh[fn], acc[fm][fn], 0, 0, 0);
                acc[fm][fn] = __builtin_amdgcn_mfma_f32_16x16x32_bf16(ah[fm], bl[fn], acc[fm][fn], 0, 0, 0);
                acc[fm][fn] = __builtin_amdgcn_mfma_f32_16x16x32_bf16(al[fm], bh[fn], acc[fm][fn], 0, 0, 0);
            }
        __syncthreads();
    }

    const int lr = l & 15, lg = l >> 4;
    const float* sqb = sq + z * Nn_;
    float* ob = d2 + (long)z * Nn_ * Nn_;
    #pragma unroll
    for (int fm = 0; fm < 4; ++fm)
        #pragma unroll
        for (int fn = 0; fn < 2; ++fn)
            #pragma unroll
            for (int rg = 0; rg < 4; ++rg) {
                const int gm = bm + wm * 64 + fm * 16 + lg * 4 + rg;
                const int gc = bn + wn * 32 + fn * 16 + lr;
                float v = sqb[gm] + sqb[gc] - 2.0f * acc[fm][fn][rg];
                if (gm == gc) v = INFINITY;
                ob[(long)gm * Nn_ + gc] = v;
                if (j == 1) ob[(long)gc * Nn_ + gm] = v;   // mirror (symmetric), gm<128<=gc
            }
}

// ---------------- zero-fill ----------------
__global__ __launch_bounds__(256) void clear_k(float4* __restrict__ p)
{
    p[(long)blockIdx.x * 256 + threadIdx.x] = make_float4(0.f, 0.f, 0.f, 0.f);
}

// ---------------- fused prep, WAVE-PER-ROW: tokens -> hilo + sq + LN1(b0) ----------------
__global__ __launch_bounds__(256) void prep_k(const float* __restrict__ in, u16* __restrict__ hilo,
    float* __restrict__ sq, u16* __restrict__ lnout,
    const float* __restrict__ g, const float* __restrict__ bvec)
{
    const int w = threadIdx.x >> 6, lane = threadIdx.x & 63;
    const long row = (long)blockIdx.x * 4 + w;
    const long base = row * Dd;

    float xs[16];
    #pragma unroll
    for (int c = 0; c < 4; ++c) {
        const int idx = c * 256 + lane * 4;
        const float4 v = *(const float4*)&in[base + idx];
        xs[c*4+0] = v.x; xs[c*4+1] = v.y; xs[c*4+2] = v.z; xs[c*4+3] = v.w;
        u16x4 hi, lo;
        #pragma unroll
        for (int j = 0; j < 4; ++j) {
            hi[j] = bfb(xs[c*4+j]);
            lo[j] = bfb(xs[c*4+j] - fromb(hi[j]));
        }
        *(u16x4*)&hilo[row * 2048 + idx]        = hi;
        *(u16x4*)&hilo[row * 2048 + 1024 + idx] = lo;
    }

    float s = 0.f, s2 = 0.f;
    #pragma unroll
    for (int i = 0; i < 16; ++i) { s += xs[i]; s2 += xs[i] * xs[i]; }
    #pragma unroll
    for (int o = 32; o > 0; o >>= 1) { s += __shfl_xor(s, o); s2 += __shfl_xor(s2, o); }
    if (lane == 0) sq[row] = s2;
    const float mean = s * (1.0f / Dd);
    const float rstd = rsqrtf(s2 * (1.0f / Dd) - mean * mean + LN_EPS);

    #pragma unroll
    for (int c = 0; c < 4; ++c) {
        const int idx = c * 256 + lane * 4;
        const float4 gv = *(const float4*)&g[idx];
        const float4 bv = *(const float4*)&bvec[idx];
        const float gs[4] = {gv.x, gv.y, gv.z, gv.w};
        const float bs[4] = {bv.x, bv.y, bv.z, bv.w};
        u16x4 ov;
        #pragma unroll
        for (int j = 0; j < 4; ++j) ov[j] = bfb((xs[c*4+j] - mean) * rstd * gs[j] + bs[j]);
        *(u16x4*)&lnout[base + idx] = ov;
    }
}

// ---------------- weight transpose-convert: in [R][C] f32 -> out [C][R] bf16, batched ----------------
__global__ __launch_bounds__(256) void transw_k(const float* __restrict__ in, u16* __restrict__ out,
                                                int R, int C, long sIn, long sOut)
{
    __shared__ u16 t[32][33];
    const int z = blockIdx.z;
    const float* ib = in + (long)z * sIn;
    u16* ob = out + (long)z * sOut;
    const int r0 = blockIdx.y * 32, c0 = blockIdx.x * 32;
    const int tr = threadIdx.x >> 3, tc4 = (threadIdx.x & 7) * 4;
    const float* p = ib + (long)(r0 + tr) * C + c0 + tc4;
    #pragma unroll
    for (int j = 0; j < 4; ++j) t[tr][tc4 + j] = bfb(p[j]);
    __syncthreads();
    u16* q = ob + (long)(c0 + tr) * R + r0 + tc4;
    #pragma unroll
    for (int j = 0; j < 4; ++j) q[j] = t[tc4 + j][tr];
}

// ---------------- classifier weight transpose: Wc [1024][1000] f32 -> WcT [1000][1024] f32 ----------------
__global__ __launch_bounds__(256) void transc_k(const float* __restrict__ Wc, float* __restrict__ WcT)
{
    __shared__ float t[32][33];
    const int r0 = blockIdx.y * 32, c0 = blockIdx.x * 32;
    const int tr = threadIdx.x >> 3, tc4 = (threadIdx.x & 7) * 4;
    #pragma unroll
    for (int j = 0; j < 4; ++j) {
        const int c = c0 + tc4 + j;
        t[tr][tc4 + j] = (c < NC) ? Wc[(long)(r0 + tr) * NC + c] : 0.f;
    }
    __syncthreads();
    const int oc = c0 + tr;
    if (oc < NC) {
        #pragma unroll
        for (int j = 0; j < 4; ++j)
            WcT[(long)oc * Dd + r0 + tc4 + j] = t[tc4 + j][tr];
    }
}

// ---------------- fused residual + double-LN, WAVE-PER-ROW ----------------
template<int LAST, int XF32>
__global__ __launch_bounds__(256) void ln2fr_k(const u16* __restrict__ hsrc,
    const void* __restrict__ xinv, u16* __restrict__ xout, u16* __restrict__ lnout,
    const float* __restrict__ g2, const float* __restrict__ be2,
    const float* __restrict__ gn, const float* __restrict__ bn)
{
    const int w = threadIdx.x >> 6, lane = threadIdx.x & 63;
    const long row = (long)blockIdx.x * 4 + w;
    const long base = row * Dd;

    float xs[16];
    #pragma unroll
    for (int c = 0; c < 4; ++c) {
        const int idx = c * 256 + lane * 4;
        const u16x4 hv = *(const u16x4*)&hsrc[base + idx];
        if constexpr (XF32) {
            const float4 xv = *(const float4*)&((const float*)xinv)[base + idx];
            xs[c*4+0] = xv.x + fromb(hv[0]);
            xs[c*4+1] = xv.y + fromb(hv[1]);
            xs[c*4+2] = xv.z + fromb(hv[2]);
            xs[c*4+3] = xv.w + fromb(hv[3]);
        } else {
            const u16x4 xv = *(const u16x4*)&((const u16*)xinv)[base + idx];
            #pragma unroll
            for (int j = 0; j < 4; ++j) xs[c*4+j] = fromb(xv[j]) + fromb(hv[j]);
        }
    }

    {
        float s = 0.f, s2 = 0.f;
        #pragma unroll
        for (int i = 0; i < 16; ++i) { s += xs[i]; s2 += xs[i] * xs[i]; }
        #pragma unroll
        for (int o = 32; o > 0; o >>= 1) { s += __shfl_xor(s, o); s2 += __shfl_xor(s2, o); }
        const float mean = s * (1.0f / Dd);
        const float rstd = rsqrtf(s2 * (1.0f / Dd) - mean * mean + LN_EPS);
        #pragma unroll
        for (int c = 0; c < 4; ++c) {
            const int idx = c * 256 + lane * 4;
            const float4 gv = *(const float4*)&g2[idx];
            const float4 bv = *(const float4*)&be2[idx];
            const float gs[4] = {gv.x, gv.y, gv.z, gv.w};
            const float bs[4] = {bv.x, bv.y, bv.z, bv.w};
            #pragma unroll
            for (int j = 0; j < 4; ++j)
                xs[c*4+j] = xs[c*4+j] + gelu_f((xs[c*4+j] - mean) * rstd * gs[j] + bs[j]);
        }
    }

    float s = 0.f, s2 = 0.f;
    #pragma unroll
    for (int i = 0; i < 16; ++i) { s += xs[i]; s2 += xs[i] * xs[i]; }
    #pragma unroll
    for (int o = 32; o > 0; o >>= 1) { s += __shfl_xor(s, o); s2 += __shfl_xor(s2, o); }
    const float mean = s * (1.0f / Dd);
    const float rstd = rsqrtf(s2 * (1.0f / Dd) - mean * mean + LN_EPS);
    #pragma unroll
    for (int c = 0; c < 4; ++c) {
        const int idx = c * 256 + lane * 4;
        const float4 gv = *(const float4*)&gn[idx];
        const float4 bv = *(const float4*)&bn[idx];
        const float gs[4] = {gv.x, gv.y, gv.z, gv.w};
        const float bs[4] = {bv.x, bv.y, bv.z, bv.w};
        u16x4 ov;
        if constexpr (LAST) {
            #pragma unroll
            for (int j = 0; j < 4; ++j) ov[j] = bfb(gelu_f((xs[c*4+j] - mean) * rstd * gs[j] + bs[j]));
        } else {
            u16x4 xo;
            #pragma unroll
            for (int j = 0; j < 4; ++j) xo[j] = bfb(xs[c*4+j]);
            *(u16x4*)&xout[base + idx] = xo;
            #pragma unroll
            for (int j = 0; j < 4; ++j) ov[j] = bfb((xs[c*4+j] - mean) * rstd * gs[j] + bs[j]);
        }
        *(u16x4*)&lnout[base + idx] = ov;
    }
}

__global__ __launch_bounds__(256) void topk_k(const float* __restrict__ d2, float* __restrict__ Aout,
                                              const int* __restrict__ kptr)
{
    const int k = *kptr;
    const int wid = threadIdx.x >> 6, lane = threadIdx.x & 63;
    const long row = (long)blockIdx.x * 4 + wid;
    const long b = row >> 8;
    const int  i = (int)(row & 255);
    const float* dr = d2 + row * Nn_;
    float v[4];
    bool sel[4] = {false, false, false, false};
    #pragma unroll
    for (int c = 0; c < 4; ++c) v[c] = dr[lane + 64 * c];
    for (int it = 0; it < k; ++it) {
        float bv = INFINITY; int bi = 1 << 20;
        #pragma unroll
        for (int c = 0; c < 4; ++c) {
            const int idx = lane + 64 * c;
            if (!sel[c] && (v[c] < bv || (v[c] == bv && idx < bi))) { bv = v[c]; bi = idx; }
        }
        #pragma unroll
        for (int o = 32; o > 0; o >>= 1) {
            float ov = __shfl_xor(bv, o); int oi = __shfl_xor(bi, o);
            if (ov < bv || (ov == bv && oi < bi)) { bv = ov; bi = oi; }
        }
        #pragma unroll
        for (int c = 0; c < 4; ++c) if (lane + 64 * c == bi) sel[c] = true;
        if (lane == 0) {
            Aout[(b * Nn_ + i) * Nn_ + bi] = 1.0f;
            Aout[(b * Nn_ + bi) * Nn_ + i] = 1.0f;
        }
    }
    if (lane == 0) Aout[(b * Nn_ + i) * Nn_ + i] = 1.0f;
}

__global__ __launch_bounds__(256) void deg_k(const float* __restrict__ A, float* __restrict__ dinv)
{
    const int wid = threadIdx.x >> 6, lane = threadIdx.x & 63;
    const long row = (long)blockIdx.x * 4 + wid;
    const float* ar = A + row * Nn_;
    float s = 0.f;
    #pragma unroll
    for (int c = 0; c < 4; ++c) s += ar[lane + 64 * c];
    #pragma unroll
    for (int o = 32; o > 0; o >>= 1) s += __shfl_down(s, o);
    if (lane == 0) dinv[row] = rsqrtf(s);
}

// fused: Ahat bf16 = A*di*dj  AND  rsA[row] = rowsum(Ahat) in f32. One wave per row.
__global__ __launch_bounds__(256) void scalebf2_k(const float* __restrict__ A, const float* __restrict__ dinv,
                                                  u16* __restrict__ out, float* __restrict__ rsA)
{
    const int wid = threadIdx.x >> 6, lane = threadIdx.x & 63;
    const long row = (long)blockIdx.x * 4 + wid;
    const long b = row >> 8;
    const float di = dinv[row];
    const int j0 = lane * 4;
    const float4 dj = *(const float4*)&dinv[b * Nn_ + j0];
    const float4 a = *(const float4*)&A[row * Nn_ + j0];
    const float v0 = a.x * di * dj.x, v1 = a.y * di * dj.y, v2 = a.z * di * dj.z, v3 = a.w * di * dj.w;
    u16x4 o = { bfb(v0), bfb(v1), bfb(v2), bfb(v3) };
    *(u16x4*)&out[row * Nn_ + j0] = o;
    float s = v0 + v1 + v2 + v3;
    #pragma unroll
    for (int off = 32; off > 0; off >>= 1) s += __shfl_down(s, off);
    if (lane == 0) rsA[row] = s;
}

// mean-pool over nodes, bf16 input
__global__ __launch_bounds__(256) void poolb_k(const u16* __restrict__ y, float* __restrict__ pooled)
{
    const int d = blockIdx.x * 256 + threadIdx.x;
    const int b = blockIdx.y;
    const u16* yb = y + (long)b * Nn_ * Dd + d;
    float s = 0.f;
    #pragma unroll 4
    for (int n = 0; n < Nn_; ++n) s += fromb(yb[(long)n * Dd]);
    pooled[b * Dd + d] = s * (1.0f / Nn_);
}

// one wave per (batch, class) logit
__global__ __launch_bounds__(256) void cls2_k(const float* __restrict__ pooled, const float* __restrict__ WcT,
    const float* __restrict__ bc, float* __restrict__ out)
{
    const int w = threadIdx.x >> 6, lane = threadIdx.x & 63;
    const int c = blockIdx.x * 4 + w;
    const int b = blockIdx.y;
    const float* wr = WcT + (long)c * Dd;
    const float* p  = pooled + (long)b * Dd;
    float s = 0.f;
    #pragma unroll
    for (int it = 0; it < 4; ++it) {
        const float4 wv = *(const float4*)&wr[it * 256 + lane * 4];
        const float4 pv = *(const float4*)&p[it * 256 + lane * 4];
        s += wv.x * pv.x + wv.y * pv.y + wv.z * pv.z + wv.w * pv.w;
    }
    #pragma unroll
    for (int o = 32; o > 0; o >>= 1) s += __shfl_down(s, o);
    if (lane == 0) out[(long)b * NC + c] = s + bc[c];
}

extern "C" void kernel_launch(void* const* d_in, const int* in_sizes, int n_in,
                              void* d_out, int out_size, void* d_ws, size_t ws_size,
                              hipStream_t stream)
{
    const float* tokens = (const float*)d_in[0];
    const float* W1  = (const float*)d_in[1];
    const float* b1  = (const float*)d_in[2];
    const float* W2  = (const float*)d_in[3];
    const float* b2  = (const float*)d_in[4];
    const float* g1  = (const float*)d_in[5];
    const float* be1 = (const float*)d_in[6];
    const float* g2  = (const float*)d_in[7];
    const float* be2 = (const float*)d_in[8];
    const float* gr  = (const float*)d_in[9];
    const float* br  = (const float*)d_in[10];
    const float* Wc  = (const float*)d_in[11];
    const float* bc  = (const float*)d_in[12];
    const int*   kptr = (const int*)d_in[13];

    constexpr long SZ_XD = (long)Bb * Nn_ * Dd;   // 16.78M elems
    constexpr long SZ_A  = (long)Bb * Nn_ * Nn_;  //  4.19M elems

    // workspace carve (~155 MB; <= round-1-proven 218.5 MB)
    char* wp = (char*)d_ws;
    u16*   xbf    = (u16*)wp;   wp += SZ_XD * 2;   // residual trunk bf16 (kNN phase: AmatF f32)
    u16*   hbuf   = (u16*)wp;   wp += SZ_XD * 2;   // lin2' output h bf16 (kNN phase: d2f f32)
    u16*   bufA   = (u16*)wp;   wp += SZ_XD * 2;   // hilo lower | AZ | readout bf16
    u16*   bufB   = (u16*)wp;   wp += SZ_XD * 2;   // hilo upper | Y1t
    u16*   bufC   = (u16*)wp;   wp += SZ_XD * 2;   // LN1 output bf16 (lin1 A-operand)
    u16*   AmatBF = (u16*)wp;   wp += SZ_A * 2;
    u16*   W1t    = (u16*)wp;   wp += 2L * Dd * Hh * 2;
    u16*   W2t    = (u16*)wp;   wp += 2L * Hh * Dd * 2;
    float* WcT    = (float*)wp; wp += (long)NC * Dd * 4;
    float* sq     = (float*)wp; wp += (long)Bb * Nn_ * 4;
    float* dinv   = (float*)wp; wp += (long)Bb * Nn_ * 4;
    float* rsA    = (float*)wp; wp += (long)Bb * Nn_ * 4;
    float* pooled = (float*)wp; wp += (long)Bb * Dd * 4;

    // phase aliases (lifetimes disjoint):
    u16*   hilo  = bufA;            // [B*N][2048] bf16 hi|lo spans bufA+bufB, dead after d2mm
    float* d2f   = (float*)hbuf;    // f32 distances, dead after topk; h first written iter0 lin2'
    float* AmatF = (float*)xbf;     // f32 adjacency, dead after scalebf2; x first written iter0 ln2fr
    u16*   robuf = bufA;            // readout bf16 (AZ dead after lin2' of last iter)

    const dim3 blk(256);
    const dim3 blk8(512);

    // ---- fused prep (wave-per-row): tokens -> hilo + sq + LN1(block0) in ONE pass ----
    prep_k<<<Bb * Nn_ / 4, blk, 0, stream>>>(tokens, hilo, sq, bufC, g1, be1);

    // ---- kNN adjacency: triangle + XCD-swizzled d2, 8-wave blocks ----
    d2mm_k<<<192, blk8, 0, stream>>>(hilo, sq, d2f);
    clear_k<<<(int)(SZ_A / 4 / 256), blk, 0, stream>>>((float4*)AmatF);
    topk_k<<<Bb * Nn_ / 4, blk, 0, stream>>>(d2f, AmatF, kptr);
    deg_k<<<Bb * Nn_ / 4, blk, 0, stream>>>(AmatF, dinv);
    scalebf2_k<<<Bb * Nn_ / 4, blk, 0, stream>>>(AmatF, dinv, AmatBF, rsA);

    // ---- weight transposes ----
    transw_k<<<dim3(Hh / 32, Dd / 32, 2), blk, 0, stream>>>(W1, W1t, Dd, Hh, (long)Dd * Hh, (long)Hh * Dd);
    transw_k<<<dim3(Dd / 32, Hh / 32, 2), blk, 0, stream>>>(W2, W2t, Hh, Dd, (long)Hh * Dd, (long)Dd * Hh);
    transc_k<<<dim3(32, Dd / 32), blk, 0, stream>>>(Wc, WcT);

    // ---- GraphBlocks ----
    for (int i = 0; i < 2; ++i) {
        // lin1: Y1t[b][512][256] = (LN1 @ W1 + b1)^T   (nx=4, ny=128, nz=1 -> 512 blocks)
        mgemm_k<EP_BIAS_BF_CT><<<512, blk8, 0, stream>>>(
            bufC, W1t + (long)i * Hh * Dd, bufB, b1 + i * Hh, nullptr,
            Bb * Nn_, Hh, Dd, 0, 0, 0, 2, 7, 0);
        // fused AY double-multiply: AZ[b][256][512] = Ahat @ gelu(Ahat @ Y1)   (256 blocks)
        ayy_k<<<256, blk8, 0, stream>>>(AmatBF, bufB, bufA);
        // lin2': h[16384][1024] = AZ @ W2 + rsA*b2   (nx=8, ny=128, nz=1 -> 1024 blocks)
        mgemm_k<EP_SBIAS_BF><<<1024, blk8, 0, stream>>>(
            bufA, W2t + (long)i * Dd * Hh, hbuf, b2 + i * Dd, rsA,
            Bb * Nn_, Dd, Hh, 0, 0, 0, 3, 7, 0);
        // fused residual + double-LN (wave-per-row)
        if (i == 0)
            ln2fr_k<0, 1><<<Bb * Nn_ / 4, blk, 0, stream>>>(hbuf, tokens, xbf, bufC,
                g2, be2, g1 + Dd, be1 + Dd);
        else
            ln2fr_k<1, 0><<<Bb * Nn_ / 4, blk, 0, stream>>>(hbuf, xbf, nullptr, robuf,
                g2 + Dd, be2 + Dd, gr, br);
    }

    // ---- pool + classifier ----
    poolb_k<<<dim3(Dd / 256, Bb), blk, 0, stream>>>(robuf, pooled);
    cls2_k<<<dim3(NC / 4, Bb), blk, 0, stream>>>(pooled, WcT, bc, (float*)d_out);
}

// Round 14
// 358.855 us; speedup vs baseline: 1.0214x; 1.0214x over previous
//
#include <hip/hip_runtime.h>
#include <hip/hip_bf16.h>
#include <math.h>

constexpr int Bb  = 64;    // batch
constexpr int Nn_ = 256;   // nodes
constexpr int Dd  = 1024;  // feature dim
constexpr int Hh  = 512;   // hidden
constexpr int NC  = 1000;  // classes
constexpr float LN_EPS = 1e-5f;

#define DEV __device__ __forceinline__

typedef unsigned short u16;
typedef __attribute__((ext_vector_type(8))) short bf16x8;   // 8 bf16 = 4 VGPR
typedef __attribute__((ext_vector_type(4))) float f32x4;
typedef __attribute__((ext_vector_type(4))) unsigned short u16x4;

// fast erf: Abramowitz-Stegun 7.1.26 (abs err < 1.5e-7) with HW rcp + HW exp.
DEV float erf_fast(float x) {
    const float ax = fabsf(x);
    const float t = __builtin_amdgcn_rcpf(fmaf(0.3275911f, ax, 1.0f));
    const float y = t * (0.254829592f + t * (-0.284496736f + t * (1.421413741f +
                    t * (-1.453152027f + t * 1.061405429f))));
    const float r = 1.0f - y * __expf(-ax * ax);
    return copysignf(r, x);
}
DEV float gelu_f(float x) { return 0.5f * x * (1.0f + erf_fast(x * 0.70710678118654752f)); }
DEV u16 bfb(float x) { __hip_bfloat16 h = __float2bfloat16(x); u16 u; __builtin_memcpy(&u, &h, 2); return u; }
DEV float fromb(u16 u) { unsigned int w = (unsigned int)u << 16; float f; __builtin_memcpy(&f, &w, 4); return f; }

// async global->LDS, 16B per lane
DEV void gload16(const void* g, void* l) {
    __builtin_amdgcn_global_load_lds(
        (const __attribute__((address_space(1))) void*)(uintptr_t)g,
        (__attribute__((address_space(3))) void*)(uintptr_t)l, 16, 0, 0);
}

// ---------------- bf16 MFMA GEMM: C = epi(A @ B), A [M,K] rm bf16, Bt [N,K] rm bf16 ----------------
// 128x128 tile, BK=32, 8 waves (2x4, per-wave 64x32), 16x16x32 MFMA, XOR slot-swizzle (rule #21).
// XCD-aware 1D grid (T1, A/B-proven round 11: -33 us).
enum { EP_BIAS_BF_CT = 0, EP_SBIAS_BF = 3 };

template<int EPI>
__global__ __launch_bounds__(512) void mgemm_k(
    const u16* __restrict__ Ag, const u16* __restrict__ Bg, void* __restrict__ Cg,
    const float* __restrict__ bias, const float* __restrict__ rsA,
    int M, int Nc, int K, long sA, long sB, long sC,
    int lognx, int logny, int lognz)
{
    __shared__ __align__(16) u16 sm[2][2][128 * 32];
    const int tid = threadIdx.x;
    const int l = tid & 63, w = tid >> 6;   // 8 waves
    const int wm = w >> 2, wn = w & 3;      // 2x4

    // XCD-aware decode (bijective; all dims are powers of 2)
    const int lid = blockIdx.x;
    const int xcd = lid & 7, idx = lid >> 3;
    int bxi, byi, z;
    if (lognz == 0) {                 // weight GEMM: group over x, spread y across XCDs
        bxi = idx & ((1 << lognx) - 1);
        byi = (xcd << (logny - 3)) | (idx >> lognx);
        z = 0;
    } else {                          // batched GEMM: group over (x,y), spread z across XCDs
        bxi = idx & ((1 << lognx) - 1);
        byi = (idx >> lognx) & ((1 << logny) - 1);
        z = (xcd << (lognz - 3)) | (idx >> (lognx + logny));
    }
    const int bm = byi * 128, bn = bxi * 128;

    const u16* Ab  = Ag + (long)z * sA;
    const u16* Bbp = Bg + (long)z * sB;

    f32x4 acc[4][2] = {};
    const int nt = K >> 5;

    auto stage = [&](int db, int t) {
        const long kk = (long)t << 5;
        const int o = tid * 16;                         // 512 lanes x 16B = full 8KB operand tile
        const int r = o >> 6;                           // tile row 0..127
        const int g = ((o >> 4) & 3) ^ ((r >> 1) & 3);  // inverse-swizzled k-slot
        gload16(Ab  + (long)(bm + r) * K + kk + g * 8, (char*)&sm[db][0][0] + o);
        gload16(Bbp + (long)(bn + r) * K + kk + g * 8, (char*)&sm[db][1][0] + o);
    };

    stage(0, 0);
    __syncthreads();
    for (int t = 0; t < nt; ++t) {
        const int db = t & 1;
        if (t + 1 < nt) stage(db ^ 1, t + 1);
        const int lr = l & 15, g = l >> 4;
        bf16x8 af[4], bfr[2];
        #pragma unroll
        for (int fm = 0; fm < 4; ++fm) {
            const int r = wm * 64 + fm * 16 + lr;
            af[fm] = *(const bf16x8*)((const char*)&sm[db][0][0] + r * 64 + ((g ^ ((r >> 1) & 3)) << 4));
        }
        #pragma unroll
        for (int fn = 0; fn < 2; ++fn) {
            const int r = wn * 32 + fn * 16 + lr;
            bfr[fn] = *(const bf16x8*)((const char*)&sm[db][1][0] + r * 64 + ((g ^ ((r >> 1) & 3)) << 4));
        }
        #pragma unroll
        for (int fm = 0; fm < 4; ++fm)
            #pragma unroll
            for (int fn = 0; fn < 2; ++fn)
                acc[fm][fn] = __builtin_amdgcn_mfma_f32_16x16x32_bf16(af[fm], bfr[fn], acc[fm][fn], 0, 0, 0);
        __syncthreads();
    }

    // epilogue: C/D layout col=lane&15, row=(lane>>4)*4+reg (m89-verified)
    const int lr = l & 15, lg = l >> 4;
    if constexpr (EPI == EP_SBIAS_BF) {
        u16* Cb = (u16*)Cg;
        #pragma unroll
        for (int fm = 0; fm < 4; ++fm)
            #pragma unroll
            for (int fn = 0; fn < 2; ++fn) {
                const int gc = bn + wn * 32 + fn * 16 + lr;
                const float bv = bias[gc];
                #pragma unroll
                for (int rg = 0; rg < 4; ++rg) {
                    const int gm = bm + wm * 64 + fm * 16 + lg * 4 + rg;
                    Cb[(long)gm * Nc + gc] = bfb(acc[fm][fn][rg] + rsA[gm] * bv);
                }
            }
    } else {  // EP_BIAS_BF_CT: transposed store out[gm>>8][gc][gm&255]
        #pragma unroll
        for (int fm = 0; fm < 4; ++fm) {
            const int gm0 = bm + wm * 64 + fm * 16 + lg * 4;
            #pragma unroll
            for (int fn = 0; fn < 2; ++fn) {
                const int gc = bn + wn * 32 + fn * 16 + lr;
                const float bv = bias[gc];
                u16x4 vals;
                #pragma unroll
                for (int rg = 0; rg < 4; ++rg) vals[rg] = bfb(acc[fm][fn][rg] + bv);
                const long addr = (long)(gm0 >> 8) * ((long)Nc * 256) + (long)gc * 256 + (gm0 & 255);
                *(u16x4*)&((u16*)Cg)[addr] = vals;
            }
        }
    }
}

// ---------------- fused graph double-multiply: AZ = Ahat @ gelu(Ahat @ Y1), column-sliced ----------------
// One block per (batch z, 128-col slice cs of Hh). A-fragments preloaded in registers (af[4][8] = 128
// VGPR) and reused for BOTH multiplies. __launch_bounds__(512) WITHOUT min-waves: ~230 VGPR fits the
// 256-VGPR tier (m69: 8 waves/CU) with NO spills; LDS (128KB) limits to 1 block/CU anyway -- round-12's
// ",2" capped the allocator at 128 VGPR and forced spills (the r12 underperformance).
// LDS: sY [128 c][256 k] u16 XOR-swizzled (rule #21), sZ [128 c][256 r] swizzled transpose-store.
__global__ __launch_bounds__(512) void ayy_k(
    const u16* __restrict__ Ahat, const u16* __restrict__ Y1t, u16* __restrict__ AZ)
{
    __shared__ __align__(16) u16 sY[128 * 256];
    __shared__ __align__(16) u16 sZ[128 * 256];

    const int tid = threadIdx.x;
    const int l = tid & 63, w = tid >> 6;
    const int wm = w >> 1, wn = w & 1;

    const int lid = blockIdx.x;                 // 256 blocks; all 4 slices of a batch on one XCD
    const int xcd = lid & 7, idx = lid >> 3;
    const int cs = idx & 3;
    const int z  = xcd * 8 + (idx >> 2);

    const u16* Ab = Ahat + (long)z * Nn_ * Nn_;
    const u16* Yb = Y1t + (long)z * Hh * Nn_ + (long)(cs * 128) * Nn_;  // [128 c][256 k]

    // stage Y1 slice -> sY, swizzle byte ^= ((c&7)<<4) applied via pre-swizzled SOURCE
    #pragma unroll
    for (int i = 0; i < 8; ++i) {
        const int o = i * 8192 + tid * 16;      // linear LDS byte offset
        const int c = o >> 9;
        const int wb = (o & 511) ^ ((c & 7) << 4);
        gload16((const char*)Yb + (long)c * 512 + wb, (char*)sY + o);
    }

    // preload A fragments af[fm][ks]: row r = wm*64+fm*16+(l&15), k = ks*32+(l>>4)*8  (128 VGPR)
    const int lr = l & 15, g = l >> 4;
    bf16x8 af[4][8];
    #pragma unroll
    for (int fm = 0; fm < 4; ++fm) {
        const int r = wm * 64 + fm * 16 + lr;
        #pragma unroll
        for (int ks = 0; ks < 8; ++ks)
            af[fm][ks] = *(const bf16x8*)(Ab + (long)r * Nn_ + ks * 32 + g * 8);
    }

    __syncthreads();

    // ---- mult1: Z1 = gelu(A @ Y1slice) ----
    f32x4 acc[4][4] = {};
    #pragma unroll
    for (int ks = 0; ks < 8; ++ks) {
        bf16x8 bfr[4];
        #pragma unroll
        for (int fn = 0; fn < 4; ++fn) {
            const int c = wn * 64 + fn * 16 + lr;
            const int kb = (ks * 64 + g * 16) ^ ((c & 7) << 4);
            bfr[fn] = *(const bf16x8*)((const char*)sY + c * 512 + kb);
        }
        #pragma unroll
        for (int fm = 0; fm < 4; ++fm)
            #pragma unroll
            for (int fn = 0; fn < 4; ++fn)
                acc[fm][fn] = __builtin_amdgcn_mfma_f32_16x16x32_bf16(af[fm][ks], bfr[fn], acc[fm][fn], 0, 0, 0);
    }
    // gelu + pack + swizzled transpose-store into sZ[c][r]: byte = c*512 + ((r*2) ^ ((c&7)<<4))
    #pragma unroll
    for (int fm = 0; fm < 4; ++fm)
        #pragma unroll
        for (int fn = 0; fn < 4; ++fn) {
            const int c = wn * 64 + fn * 16 + lr;
            const int r0 = wm * 64 + fm * 16 + g * 4;
            u16x4 v;
            #pragma unroll
            for (int rg = 0; rg < 4; ++rg) v[rg] = bfb(gelu_f(acc[fm][fn][rg]));
            *(u16x4*)((char*)sZ + c * 512 + ((r0 * 2) ^ ((c & 7) << 4))) = v;
            acc[fm][fn] = f32x4{0.f, 0.f, 0.f, 0.f};   // reset in place for mult2
        }
    __syncthreads();

    // ---- mult2: AZ = A @ Z1  (same af registers, k runs over rows r of Z1) ----
    #pragma unroll
    for (int ks = 0; ks < 8; ++ks) {
        bf16x8 bfr[4];
        #pragma unroll
        for (int fn = 0; fn < 4; ++fn) {
            const int c = wn * 64 + fn * 16 + lr;
            const int kb = (ks * 64 + g * 16) ^ ((c & 7) << 4);
            bfr[fn] = *(const bf16x8*)((const char*)sZ + c * 512 + kb);
        }
        #pragma unroll
        for (int fm = 0; fm < 4; ++fm)
            #pragma unroll
            for (int fn = 0; fn < 4; ++fn)
                acc[fm][fn] = __builtin_amdgcn_mfma_f32_16x16x32_bf16(af[fm][ks], bfr[fn], acc[fm][fn], 0, 0, 0);
    }
    // write AZ row-major [b][256][512]
    u16* Ob = AZ + (long)z * Nn_ * Hh + cs * 128;
    #pragma unroll
    for (int fm = 0; fm < 4; ++fm)
        #pragma unroll
        for (int fn = 0; fn < 4; ++fn)
            #pragma unroll
            for (int rg = 0; rg < 4; ++rg) {
                const int r = wm * 64 + fm * 16 + g * 4 + rg;
                const int c = wn * 64 + fn * 16 + lr;
                Ob[(long)r * Hh + c] = bfb(acc[fm][fn][rg]);
            }
}

// ---------------- d2 gram via split-bf16 (hi*hi + hi*lo + lo*hi), symmetric-triangle + XCD swizzle ----
__global__ __launch_bounds__(512) void d2mm_k(
    const u16* __restrict__ HL, const float* __restrict__ sq, float* __restrict__ d2)
{
    __shared__ __align__(16) u16 sm[2][4][128 * 32];  // [dbuf][Ahi,Alo,Bhi,Blo]
    const int tid = threadIdx.x;
    const int l = tid & 63, w = tid >> 6;     // 8 waves
    const int wm = w >> 2, wn = w & 3;        // 2x4

    const int lid = blockIdx.x;            // 0..191
    const int xcd = lid & 7, q = lid >> 3; // q 0..23
    const int j   = q % 3;                 // triangle tile: 0=(0,0) 1=(0,128) 2=(128,128)
    const int z   = (q / 3) * 8 + xcd;     // batch, bijective over [0,64)
    const int bm  = (j == 2) ? 128 : 0;
    const int bn  = (j == 0) ? 0 : 128;

    const u16* Hb = HL + (long)z * Nn_ * 2048;

    f32x4 acc[4][2] = {};

    auto stage = [&](int db, int t) {
        const long kk = (long)t << 5;
        const int o = tid * 16;
        const int r = o >> 6;
        const int g = ((o >> 4) & 3) ^ ((r >> 1) & 3);
        const long ka = kk + g * 8;
        gload16(Hb + (long)(bm + r) * 2048 + ka,        (char*)&sm[db][0][0] + o);
        gload16(Hb + (long)(bm + r) * 2048 + 1024 + ka, (char*)&sm[db][1][0] + o);
        gload16(Hb + (long)(bn + r) * 2048 + ka,        (char*)&sm[db][2][0] + o);
        gload16(Hb + (long)(bn + r) * 2048 + 1024 + ka, (char*)&sm[db][3][0] + o);
    };

    stage(0, 0);
    __syncthreads();
    for (int t = 0; t < 32; ++t) {
        const int db = t & 1;
        if (t + 1 < 32) stage(db ^ 1, t + 1);
        const int lr = l & 15, g = l >> 4;
        bf16x8 ah[4], al[4], bh[2], bl[2];
        #pragma unroll
        for (int fm = 0; fm < 4; ++fm) {
            const int r = wm * 64 + fm * 16 + lr;
            const int off = r * 64 + ((g ^ ((r >> 1) & 3)) << 4);
            ah[fm] = *(const bf16x8*)((const char*)&sm[db][0][0] + off);
            al[fm] = *(const bf16x8*)((const char*)&sm[db][1][0] + off);
        }
        #pragma unroll
        for (int fn = 0; fn < 2; ++fn) {
            const int r = wn * 32 + fn * 16 + lr;
            const int off = r * 64 + ((g ^ ((r >> 1) & 3)) << 4);
            bh[fn] = *(const bf16x8*)((const char*)&sm[db][2][0] + off);
            bl[fn] = *(const bf16x8*)((const char*)&sm[db][3][0] + off);
        }
        #pragma unroll
        for (int fm = 0; fm < 4; ++fm)
            #pragma unroll
            for (int fn = 0; fn < 2; ++fn) {
                acc[fm][fn] = __builtin_amdgcn_mfma_f32_16x16x32_bf16(ah[fm], bh[fn], acc[fm][fn], 0, 0, 0);
                acc[fm][fn] = __builtin_amdgcn_mfma_f32_16x16x32_bf16(ah[fm], bl[fn], acc[fm][fn], 0, 0, 0);
                acc[fm][fn] = __builtin_amdgcn_mfma_f32_16x16x32_bf16(al[fm], bh[fn], acc[fm][fn], 0, 0, 0);
            }
        __syncthreads();
    }

    const int lr = l & 15, lg = l >> 4;
    const float* sqb = sq + z * Nn_;
    float* ob = d2 + (long)z * Nn_ * Nn_;
    #pragma unroll
    for (int fm = 0; fm < 4; ++fm)
        #pragma unroll
        for (int fn = 0; fn < 2; ++fn)
            #pragma unroll
            for (int rg = 0; rg < 4; ++rg) {
                const int gm = bm + wm * 64 + fm * 16 + lg * 4 + rg;
                const int gc = bn + wn * 32 + fn * 16 + lr;
                float v = sqb[gm] + sqb[gc] - 2.0f * acc[fm][fn][rg];
                if (gm == gc) v = INFINITY;
                ob[(long)gm * Nn_ + gc] = v;
                if (j == 1) ob[(long)gc * Nn_ + gm] = v;   // mirror (symmetric), gm<128<=gc
            }
}

// ---------------- zero-fill ----------------
__global__ __launch_bounds__(256) void clear_k(float4* __restrict__ p)
{
    p[(long)blockIdx.x * 256 + threadIdx.x] = make_float4(0.f, 0.f, 0.f, 0.f);
}

// ---------------- fused prep, WAVE-PER-ROW: tokens -> hilo + sq + LN1(b0) ----------------
__global__ __launch_bounds__(256) void prep_k(const float* __restrict__ in, u16* __restrict__ hilo,
    float* __restrict__ sq, u16* __restrict__ lnout,
    const float* __restrict__ g, const float* __restrict__ bvec)
{
    const int w = threadIdx.x >> 6, lane = threadIdx.x & 63;
    const long row = (long)blockIdx.x * 4 + w;
    const long base = row * Dd;

    float xs[16];
    #pragma unroll
    for (int c = 0; c < 4; ++c) {
        const int idx = c * 256 + lane * 4;
        const float4 v = *(const float4*)&in[base + idx];
        xs[c*4+0] = v.x; xs[c*4+1] = v.y; xs[c*4+2] = v.z; xs[c*4+3] = v.w;
        u16x4 hi, lo;
        #pragma unroll
        for (int j = 0; j < 4; ++j) {
            hi[j] = bfb(xs[c*4+j]);
            lo[j] = bfb(xs[c*4+j] - fromb(hi[j]));
        }
        *(u16x4*)&hilo[row * 2048 + idx]        = hi;
        *(u16x4*)&hilo[row * 2048 + 1024 + idx] = lo;
    }

    float s = 0.f, s2 = 0.f;
    #pragma unroll
    for (int i = 0; i < 16; ++i) { s += xs[i]; s2 += xs[i] * xs[i]; }
    #pragma unroll
    for (int o = 32; o > 0; o >>= 1) { s += __shfl_xor(s, o); s2 += __shfl_xor(s2, o); }
    if (lane == 0) sq[row] = s2;
    const float mean = s * (1.0f / Dd);
    const float rstd = rsqrtf(s2 * (1.0f / Dd) - mean * mean + LN_EPS);

    #pragma unroll
    for (int c = 0; c < 4; ++c) {
        const int idx = c * 256 + lane * 4;
        const float4 gv = *(const float4*)&g[idx];
        const float4 bv = *(const float4*)&bvec[idx];
        const float gs[4] = {gv.x, gv.y, gv.z, gv.w};
        const float bs[4] = {bv.x, bv.y, bv.z, bv.w};
        u16x4 ov;
        #pragma unroll
        for (int j = 0; j < 4; ++j) ov[j] = bfb((xs[c*4+j] - mean) * rstd * gs[j] + bs[j]);
        *(u16x4*)&lnout[base + idx] = ov;
    }
}

// ---------------- weight transpose-convert: in [R][C] f32 -> out [C][R] bf16, batched ----------------
__global__ __launch_bounds__(256) void transw_k(const float* __restrict__ in, u16* __restrict__ out,
                                                int R, int C, long sIn, long sOut)
{
    __shared__ u16 t[32][33];
    const int z = blockIdx.z;
    const float* ib = in + (long)z * sIn;
    u16* ob = out + (long)z * sOut;
    const int r0 = blockIdx.y * 32, c0 = blockIdx.x * 32;
    const int tr = threadIdx.x >> 3, tc4 = (threadIdx.x & 7) * 4;
    const float* p = ib + (long)(r0 + tr) * C + c0 + tc4;
    #pragma unroll
    for (int j = 0; j < 4; ++j) t[tr][tc4 + j] = bfb(p[j]);
    __syncthreads();
    u16* q = ob + (long)(c0 + tr) * R + r0 + tc4;
    #pragma unroll
    for (int j = 0; j < 4; ++j) q[j] = t[tc4 + j][tr];
}

// ---------------- classifier weight transpose: Wc [1024][1000] f32 -> WcT [1000][1024] f32 ----------------
__global__ __launch_bounds__(256) void transc_k(const float* __restrict__ Wc, float* __restrict__ WcT)
{
    __shared__ float t[32][33];
    const int r0 = blockIdx.y * 32, c0 = blockIdx.x * 32;
    const int tr = threadIdx.x >> 3, tc4 = (threadIdx.x & 7) * 4;
    #pragma unroll
    for (int j = 0; j < 4; ++j) {
        const int c = c0 + tc4 + j;
        t[tr][tc4 + j] = (c < NC) ? Wc[(long)(r0 + tr) * NC + c] : 0.f;
    }
    __syncthreads();
    const int oc = c0 + tr;
    if (oc < NC) {
        #pragma unroll
        for (int j = 0; j < 4; ++j)
            WcT[(long)oc * Dd + r0 + tc4 + j] = t[tc4 + j][tr];
    }
}

// ---------------- fused residual + double-LN, WAVE-PER-ROW ----------------
template<int LAST, int XF32>
__global__ __launch_bounds__(256) void ln2fr_k(const u16* __restrict__ hsrc,
    const void* __restrict__ xinv, u16* __restrict__ xout, u16* __restrict__ lnout,
    const float* __restrict__ g2, const float* __restrict__ be2,
    const float* __restrict__ gn, const float* __restrict__ bn)
{
    const int w = threadIdx.x >> 6, lane = threadIdx.x & 63;
    const long row = (long)blockIdx.x * 4 + w;
    const long base = row * Dd;

    float xs[16];
    #pragma unroll
    for (int c = 0; c < 4; ++c) {
        const int idx = c * 256 + lane * 4;
        const u16x4 hv = *(const u16x4*)&hsrc[base + idx];
        if constexpr (XF32) {
            const float4 xv = *(const float4*)&((const float*)xinv)[base + idx];
            xs[c*4+0] = xv.x + fromb(hv[0]);
            xs[c*4+1] = xv.y + fromb(hv[1]);
            xs[c*4+2] = xv.z + fromb(hv[2]);
            xs[c*4+3] = xv.w + fromb(hv[3]);
        } else {
            const u16x4 xv = *(const u16x4*)&((const u16*)xinv)[base + idx];
            #pragma unroll
            for (int j = 0; j < 4; ++j) xs[c*4+j] = fromb(xv[j]) + fromb(hv[j]);
        }
    }

    {
        float s = 0.f, s2 = 0.f;
        #pragma unroll
        for (int i = 0; i < 16; ++i) { s += xs[i]; s2 += xs[i] * xs[i]; }
        #pragma unroll
        for (int o = 32; o > 0; o >>= 1) { s += __shfl_xor(s, o); s2 += __shfl_xor(s2, o); }
        const float mean = s * (1.0f / Dd);
        const float rstd = rsqrtf(s2 * (1.0f / Dd) - mean * mean + LN_EPS);
        #pragma unroll
        for (int c = 0; c < 4; ++c) {
            const int idx = c * 256 + lane * 4;
            const float4 gv = *(const float4*)&g2[idx];
            const float4 bv = *(const float4*)&be2[idx];
            const float gs[4] = {gv.x, gv.y, gv.z, gv.w};
            const float bs[4] = {bv.x, bv.y, bv.z, bv.w};
            #pragma unroll
            for (int j = 0; j < 4; ++j)
                xs[c*4+j] = xs[c*4+j] + gelu_f((xs[c*4+j] - mean) * rstd * gs[j] + bs[j]);
        }
    }

    float s = 0.f, s2 = 0.f;
    #pragma unroll
    for (int i = 0; i < 16; ++i) { s += xs[i]; s2 += xs[i] * xs[i]; }
    #pragma unroll
    for (int o = 32; o > 0; o >>= 1) { s += __shfl_xor(s, o); s2 += __shfl_xor(s2, o); }
    const float mean = s * (1.0f / Dd);
    const float rstd = rsqrtf(s2 * (1.0f / Dd) - mean * mean + LN_EPS);
    #pragma unroll
    for (int c = 0; c < 4; ++c) {
        const int idx = c * 256 + lane * 4;
        const float4 gv = *(const float4*)&gn[idx];
        const float4 bv = *(const float4*)&bn[idx];
        const float gs[4] = {gv.x, gv.y, gv.z, gv.w};
        const float bs[4] = {bv.x, bv.y, bv.z, bv.w};
        u16x4 ov;
        if constexpr (LAST) {
            #pragma unroll
            for (int j = 0; j < 4; ++j) ov[j] = bfb(gelu_f((xs[c*4+j] - mean) * rstd * gs[j] + bs[j]));
        } else {
            u16x4 xo;
            #pragma unroll
            for (int j = 0; j < 4; ++j) xo[j] = bfb(xs[c*4+j]);
            *(u16x4*)&xout[base + idx] = xo;
            #pragma unroll
            for (int j = 0; j < 4; ++j) ov[j] = bfb((xs[c*4+j] - mean) * rstd * gs[j] + bs[j]);
        }
        *(u16x4*)&lnout[base + idx] = ov;
    }
}

__global__ __launch_bounds__(256) void topk_k(const float* __restrict__ d2, float* __restrict__ Aout,
                                              const int* __restrict__ kptr)
{
    const int k = *kptr;
    const int wid = threadIdx.x >> 6, lane = threadIdx.x & 63;
    const long row = (long)blockIdx.x * 4 + wid;
    const long b = row >> 8;
    const int  i = (int)(row & 255);
    const float* dr = d2 + row * Nn_;
    float v[4];
    bool sel[4] = {false, false, false, false};
    #pragma unroll
    for (int c = 0; c < 4; ++c) v[c] = dr[lane + 64 * c];
    for (int it = 0; it < k; ++it) {
        float bv = INFINITY; int bi = 1 << 20;
        #pragma unroll
        for (int c = 0; c < 4; ++c) {
            const int idx = lane + 64 * c;
            if (!sel[c] && (v[c] < bv || (v[c] == bv && idx < bi))) { bv = v[c]; bi = idx; }
        }
        #pragma unroll
        for (int o = 32; o > 0; o >>= 1) {
            float ov = __shfl_xor(bv, o); int oi = __shfl_xor(bi, o);
            if (ov < bv || (ov == bv && oi < bi)) { bv = ov; bi = oi; }
        }
        #pragma unroll
        for (int c = 0; c < 4; ++c) if (lane + 64 * c == bi) sel[c] = true;
        if (lane == 0) {
            Aout[(b * Nn_ + i) * Nn_ + bi] = 1.0f;
            Aout[(b * Nn_ + bi) * Nn_ + i] = 1.0f;
        }
    }
    if (lane == 0) Aout[(b * Nn_ + i) * Nn_ + i] = 1.0f;
}

__global__ __launch_bounds__(256) void deg_k(const float* __restrict__ A, float* __restrict__ dinv)
{
    const int wid = threadIdx.x >> 6, lane = threadIdx.x & 63;
    const long row = (long)blockIdx.x * 4 + wid;
    const float* ar = A + row * Nn_;
    float s = 0.f;
    #pragma unroll
    for (int c = 0; c < 4; ++c) s += ar[lane + 64 * c];
    #pragma unroll
    for (int o = 32; o > 0; o >>= 1) s += __shfl_down(s, o);
    if (lane == 0) dinv[row] = rsqrtf(s);
}

// fused: Ahat bf16 = A*di*dj  AND  rsA[row] = rowsum(Ahat) in f32. One wave per row.
__global__ __launch_bounds__(256) void scalebf2_k(const float* __restrict__ A, const float* __restrict__ dinv,
                                                  u16* __restrict__ out, float* __restrict__ rsA)
{
    const int wid = threadIdx.x >> 6, lane = threadIdx.x & 63;
    const long row = (long)blockIdx.x * 4 + wid;
    const long b = row >> 8;
    const float di = dinv[row];
    const int j0 = lane * 4;
    const float4 dj = *(const float4*)&dinv[b * Nn_ + j0];
    const float4 a = *(const float4*)&A[row * Nn_ + j0];
    const float v0 = a.x * di * dj.x, v1 = a.y * di * dj.y, v2 = a.z * di * dj.z, v3 = a.w * di * dj.w;
    u16x4 o = { bfb(v0), bfb(v1), bfb(v2), bfb(v3) };
    *(u16x4*)&out[row * Nn_ + j0] = o;
    float s = v0 + v1 + v2 + v3;
    #pragma unroll
    for (int off = 32; off > 0; off >>= 1) s += __shfl_down(s, off);
    if (lane == 0) rsA[row] = s;
}

// mean-pool over nodes, bf16 input
__global__ __launch_bounds__(256) void poolb_k(const u16* __restrict__ y, float* __restrict__ pooled)
{
    const int d = blockIdx.x * 256 + threadIdx.x;
    const int b = blockIdx.y;
    const u16* yb = y + (long)b * Nn_ * Dd + d;
    float s = 0.f;
    #pragma unroll 4
    for (int n = 0; n < Nn_; ++n) s += fromb(yb[(long)n * Dd]);
    pooled[b * Dd + d] = s * (1.0f / Nn_);
}

// one wave per (batch, class) logit
__global__ __launch_bounds__(256) void cls2_k(const float* __restrict__ pooled, const float* __restrict__ WcT,
    const float* __restrict__ bc, float* __restrict__ out)
{
    const int w = threadIdx.x >> 6, lane = threadIdx.x & 63;
    const int c = blockIdx.x * 4 + w;
    const int b = blockIdx.y;
    const float* wr = WcT + (long)c * Dd;
    const float* p  = pooled + (long)b * Dd;
    float s = 0.f;
    #pragma unroll
    for (int it = 0; it < 4; ++it) {
        const float4 wv = *(const float4*)&wr[it * 256 + lane * 4];
        const float4 pv = *(const float4*)&p[it * 256 + lane * 4];
        s += wv.x * pv.x + wv.y * pv.y + wv.z * pv.z + wv.w * pv.w;
    }
    #pragma unroll
    for (int o = 32; o > 0; o >>= 1) s += __shfl_down(s, o);
    if (lane == 0) out[(long)b * NC + c] = s + bc[c];
}

extern "C" void kernel_launch(void* const* d_in, const int* in_sizes, int n_in,
                              void* d_out, int out_size, void* d_ws, size_t ws_size,
                              hipStream_t stream)
{
    const float* tokens = (const float*)d_in[0];
    const float* W1  = (const float*)d_in[1];
    const float* b1  = (const float*)d_in[2];
    const float* W2  = (const float*)d_in[3];
    const float* b2  = (const float*)d_in[4];
    const float* g1  = (const float*)d_in[5];
    const float* be1 = (const float*)d_in[6];
    const float* g2  = (const float*)d_in[7];
    const float* be2 = (const float*)d_in[8];
    const float* gr  = (const float*)d_in[9];
    const float* br  = (const float*)d_in[10];
    const float* Wc  = (const float*)d_in[11];
    const float* bc  = (const float*)d_in[12];
    const int*   kptr = (const int*)d_in[13];

    constexpr long SZ_XD = (long)Bb * Nn_ * Dd;   // 16.78M elems
    constexpr long SZ_A  = (long)Bb * Nn_ * Nn_;  //  4.19M elems

    // workspace carve (~155 MB; <= round-1-proven 218.5 MB)
    char* wp = (char*)d_ws;
    u16*   xbf    = (u16*)wp;   wp += SZ_XD * 2;   // residual trunk bf16 (kNN phase: AmatF f32)
    u16*   hbuf   = (u16*)wp;   wp += SZ_XD * 2;   // lin2' output h bf16 (kNN phase: d2f f32)
    u16*   bufA   = (u16*)wp;   wp += SZ_XD * 2;   // hilo lower | AZ | readout bf16
    u16*   bufB   = (u16*)wp;   wp += SZ_XD * 2;   // hilo upper | Y1t
    u16*   bufC   = (u16*)wp;   wp += SZ_XD * 2;   // LN1 output bf16 (lin1 A-operand)
    u16*   AmatBF = (u16*)wp;   wp += SZ_A * 2;
    u16*   W1t    = (u16*)wp;   wp += 2L * Dd * Hh * 2;
    u16*   W2t    = (u16*)wp;   wp += 2L * Hh * Dd * 2;
    float* WcT    = (float*)wp; wp += (long)NC * Dd * 4;
    float* sq     = (float*)wp; wp += (long)Bb * Nn_ * 4;
    float* dinv   = (float*)wp; wp += (long)Bb * Nn_ * 4;
    float* rsA    = (float*)wp; wp += (long)Bb * Nn_ * 4;
    float* pooled = (float*)wp; wp += (long)Bb * Dd * 4;

    // phase aliases (lifetimes disjoint):
    u16*   hilo  = bufA;            // [B*N][2048] bf16 hi|lo spans bufA+bufB, dead after d2mm
    float* d2f   = (float*)hbuf;    // f32 distances, dead after topk; h first written iter0 lin2'
    float* AmatF = (float*)xbf;     // f32 adjacency, dead after scalebf2; x first written iter0 ln2fr
    u16*   robuf = bufA;            // readout bf16 (AZ dead after lin2' of last iter)

    const dim3 blk(256);
    const dim3 blk8(512);

    // ---- fused prep (wave-per-row): tokens -> hilo + sq + LN1(block0) in ONE pass ----
    prep_k<<<Bb * Nn_ / 4, blk, 0, stream>>>(tokens, hilo, sq, bufC, g1, be1);

    // ---- kNN adjacency: triangle + XCD-swizzled d2, 8-wave blocks ----
    d2mm_k<<<192, blk8, 0, stream>>>(hilo, sq, d2f);
    clear_k<<<(int)(SZ_A / 4 / 256), blk, 0, stream>>>((float4*)AmatF);
    topk_k<<<Bb * Nn_ / 4, blk, 0, stream>>>(d2f, AmatF, kptr);
    deg_k<<<Bb * Nn_ / 4, blk, 0, stream>>>(AmatF, dinv);
    scalebf2_k<<<Bb * Nn_ / 4, blk, 0, stream>>>(AmatF, dinv, AmatBF, rsA);

    // ---- weight transposes ----
    transw_k<<<dim3(Hh / 32, Dd / 32, 2), blk, 0, stream>>>(W1, W1t, Dd, Hh, (long)Dd * Hh, (long)Hh * Dd);
    transw_k<<<dim3(Dd / 32, Hh / 32, 2), blk, 0, stream>>>(W2, W2t, Hh, Dd, (long)Hh * Dd, (long)Dd * Hh);
    transc_k<<<dim3(32, Dd / 32), blk, 0, stream>>>(Wc, WcT);

    // ---- GraphBlocks ----
    for (int i = 0; i < 2; ++i) {
        // lin1: Y1t[b][512][256] = (LN1 @ W1 + b1)^T   (nx=4, ny=128, nz=1 -> 512 blocks)
        mgemm_k<EP_BIAS_BF_CT><<<512, blk8, 0, stream>>>(
            bufC, W1t + (long)i * Hh * Dd, bufB, b1 + i * Hh, nullptr,
            Bb * Nn_, Hh, Dd, 0, 0, 0, 2, 7, 0);
        // fused AY double-multiply: AZ[b][256][512] = Ahat @ gelu(Ahat @ Y1)   (256 blocks)
        ayy_k<<<256, blk8, 0, stream>>>(AmatBF, bufB, bufA);
        // lin2': h[16384][1024] = AZ @ W2 + rsA*b2   (nx=8, ny=128, nz=1 -> 1024 blocks)
        mgemm_k<EP_SBIAS_BF><<<1024, blk8, 0, stream>>>(
            bufA, W2t + (long)i * Dd * Hh, hbuf, b2 + i * Dd, rsA,
            Bb * Nn_, Dd, Hh, 0, 0, 0, 3, 7, 0);
        // fused residual + double-LN (wave-per-row)
        if (i == 0)
            ln2fr_k<0, 1><<<Bb * Nn_ / 4, blk, 0, stream>>>(hbuf, tokens, xbf, bufC,
                g2, be2, g1 + Dd, be1 + Dd);
        else
            ln2fr_k<1, 0><<<Bb * Nn_ / 4, blk, 0, stream>>>(hbuf, xbf, nullptr, robuf,
                g2 + Dd, be2 + Dd, gr, br);
    }

    // ---- pool + classifier ----
    poolb_k<<<dim3(Dd / 256, Bb), blk, 0, stream>>>(robuf, pooled);
    cls2_k<<<dim3(NC / 4, Bb), blk, 0, stream>>>(pooled, WcT, bc, (float*)d_out);
}

// Round 15
// 348.129 us; speedup vs baseline: 1.0529x; 1.0308x over previous
//
#include <hip/hip_runtime.h>
#include <hip/hip_bf16.h>
#include <math.h>

constexpr int Bb  = 64;    // batch
constexpr int Nn_ = 256;   // nodes
constexpr int Dd  = 1024;  // feature dim
constexpr int Hh  = 512;   // hidden
constexpr int NC  = 1000;  // classes
constexpr float LN_EPS = 1e-5f;

#define DEV __device__ __forceinline__

typedef unsigned short u16;
typedef __attribute__((ext_vector_type(8))) short bf16x8;   // 8 bf16 = 4 VGPR
typedef __attribute__((ext_vector_type(4))) float f32x4;
typedef __attribute__((ext_vector_type(4))) unsigned short u16x4;

// fast erf: Abramowitz-Stegun 7.1.26 (abs err < 1.5e-7) with HW rcp + HW exp.
DEV float erf_fast(float x) {
    const float ax = fabsf(x);
    const float t = __builtin_amdgcn_rcpf(fmaf(0.3275911f, ax, 1.0f));
    const float y = t * (0.254829592f + t * (-0.284496736f + t * (1.421413741f +
                    t * (-1.453152027f + t * 1.061405429f))));
    const float r = 1.0f - y * __expf(-ax * ax);
    return copysignf(r, x);
}
DEV float gelu_f(float x) { return 0.5f * x * (1.0f + erf_fast(x * 0.70710678118654752f)); }
DEV u16 bfb(float x) { __hip_bfloat16 h = __float2bfloat16(x); u16 u; __builtin_memcpy(&u, &h, 2); return u; }
DEV float fromb(u16 u) { unsigned int w = (unsigned int)u << 16; float f; __builtin_memcpy(&f, &w, 4); return f; }

// async global->LDS, 16B per lane
DEV void gload16(const void* g, void* l) {
    __builtin_amdgcn_global_load_lds(
        (const __attribute__((address_space(1))) void*)(uintptr_t)g,
        (__attribute__((address_space(3))) void*)(uintptr_t)l, 16, 0, 0);
}

// ---------------- bf16 MFMA GEMM: C = epi(A @ B), A [M,K] rm bf16, Bt [N,K] rm bf16 ----------------
// 128x128 tile, BK=32, 8 waves (2x4, per-wave 64x32), 16x16x32 MFMA, XOR slot-swizzle (rule #21).
// XCD-aware 1D grid (T1, A/B-proven round 11: -33 us). Used for lin2' only now.
enum { EP_SBIAS_BF = 3 };

template<int EPI>
__global__ __launch_bounds__(512) void mgemm_k(
    const u16* __restrict__ Ag, const u16* __restrict__ Bg, void* __restrict__ Cg,
    const float* __restrict__ bias, const float* __restrict__ rsA,
    int M, int Nc, int K, long sA, long sB, long sC,
    int lognx, int logny, int lognz)
{
    __shared__ __align__(16) u16 sm[2][2][128 * 32];
    const int tid = threadIdx.x;
    const int l = tid & 63, w = tid >> 6;   // 8 waves
    const int wm = w >> 2, wn = w & 3;      // 2x4

    // XCD-aware decode (bijective; all dims are powers of 2)
    const int lid = blockIdx.x;
    const int xcd = lid & 7, idx = lid >> 3;
    int bxi, byi, z;
    if (lognz == 0) {                 // weight GEMM: group over x, spread y across XCDs
        bxi = idx & ((1 << lognx) - 1);
        byi = (xcd << (logny - 3)) | (idx >> lognx);
        z = 0;
    } else {
        bxi = idx & ((1 << lognx) - 1);
        byi = (idx >> lognx) & ((1 << logny) - 1);
        z = (xcd << (lognz - 3)) | (idx >> (lognx + logny));
    }
    const int bm = byi * 128, bn = bxi * 128;

    const u16* Ab  = Ag + (long)z * sA;
    const u16* Bbp = Bg + (long)z * sB;

    f32x4 acc[4][2] = {};
    const int nt = K >> 5;

    auto stage = [&](int db, int t) {
        const long kk = (long)t << 5;
        const int o = tid * 16;                         // 512 lanes x 16B = full 8KB operand tile
        const int r = o >> 6;                           // tile row 0..127
        const int g = ((o >> 4) & 3) ^ ((r >> 1) & 3);  // inverse-swizzled k-slot
        gload16(Ab  + (long)(bm + r) * K + kk + g * 8, (char*)&sm[db][0][0] + o);
        gload16(Bbp + (long)(bn + r) * K + kk + g * 8, (char*)&sm[db][1][0] + o);
    };

    stage(0, 0);
    __syncthreads();
    for (int t = 0; t < nt; ++t) {
        const int db = t & 1;
        if (t + 1 < nt) stage(db ^ 1, t + 1);
        const int lr = l & 15, g = l >> 4;
        bf16x8 af[4], bfr[2];
        #pragma unroll
        for (int fm = 0; fm < 4; ++fm) {
            const int r = wm * 64 + fm * 16 + lr;
            af[fm] = *(const bf16x8*)((const char*)&sm[db][0][0] + r * 64 + ((g ^ ((r >> 1) & 3)) << 4));
        }
        #pragma unroll
        for (int fn = 0; fn < 2; ++fn) {
            const int r = wn * 32 + fn * 16 + lr;
            bfr[fn] = *(const bf16x8*)((const char*)&sm[db][1][0] + r * 64 + ((g ^ ((r >> 1) & 3)) << 4));
        }
        #pragma unroll
        for (int fm = 0; fm < 4; ++fm)
            #pragma unroll
            for (int fn = 0; fn < 2; ++fn)
                acc[fm][fn] = __builtin_amdgcn_mfma_f32_16x16x32_bf16(af[fm], bfr[fn], acc[fm][fn], 0, 0, 0);
        __syncthreads();
    }

    // epilogue: C/D layout col=lane&15, row=(lane>>4)*4+reg (m89-verified)
    const int lr = l & 15, lg = l >> 4;
    u16* Cb = (u16*)Cg;
    #pragma unroll
    for (int fm = 0; fm < 4; ++fm)
        #pragma unroll
        for (int fn = 0; fn < 2; ++fn) {
            const int gc = bn + wn * 32 + fn * 16 + lr;
            const float bv = bias[gc];
            #pragma unroll
            for (int rg = 0; rg < 4; ++rg) {
                const int gm = bm + wm * 64 + fm * 16 + lg * 4 + rg;
                Cb[(long)gm * Nc + gc] = bfb(acc[fm][fn][rg] + rsA[gm] * bv);
            }
        }
}

// ---------------- fused lin1 + graph double-multiply:
// AZ = Ahat @ gelu(Ahat @ (LN1 @ W1slice + b1)), column-sliced. One block per (batch z, 128-col slice).
// Phase 0: pipelined K=1024 GEMM Y1slice = LN1@W1sl + b1, output transposed-swizzled DIRECTLY into sY
//          (kills lin1 dispatch + Y1t 33.5MB/iter global round-trip). Staging aliased into sZ region.
// Phase 1/2: as verified ayy (A-frags preloaded in 128 VGPR, reused both multiplies; Z1 LDS-only).
// ~230 VGPR peak, no launch_bounds min-waves (r13/r14 lesson); LDS 128KB -> 1 block/CU.
__global__ __launch_bounds__(512) void ayy2_k(
    const u16* __restrict__ Ahat, const u16* __restrict__ LN1, const u16* __restrict__ W1t,
    const float* __restrict__ b1, u16* __restrict__ AZ)
{
    __shared__ __align__(16) char smem[131072];
    u16* sY = (u16*)smem;                      // [128 c][256 n] swizzled, 64KB
    u16* sZ = (u16*)(smem + 65536);            // [128 c][256 r] swizzled, 64KB (phase-0: staging alias)
    char* stA = smem + 65536;                  // [2][256*32] u16, 16KB per buf (aliases sZ)
    char* stB = smem + 65536 + 32768;          // [2][128*32] u16,  8KB per buf

    const int tid = threadIdx.x;
    const int l = tid & 63, w = tid >> 6;
    const int lr = l & 15, g = l >> 4;

    const int lid = blockIdx.x;                 // 256 blocks; all 4 slices of a batch on one XCD
    const int xcd = lid & 7, idx = lid >> 3;
    const int cs = idx & 3;
    const int z  = xcd * 8 + (idx >> 2);

    const u16* Ab  = Ahat + (long)z * Nn_ * Nn_;
    const u16* Lb  = LN1 + (long)z * Nn_ * Dd;            // [256 n][1024 k]
    const u16* Wsl = W1t + (long)(cs * 128) * Dd;         // [128 c][1024 k]
    const float* bsl = b1 + cs * 128;

    // ======== phase 0: Y1slice = LN1 @ W1sl + b1 -> sY (transposed swizzled) ========
    {
        const int rm = w >> 1, cn = w & 1;    // 4x2 wave grid: 64n x 64c per wave
        f32x4 acc[4][4] = {};

        auto stage0 = [&](int db, int t) {
            const long kk = (long)t << 5;
            #pragma unroll
            for (int i = 0; i < 2; ++i) {     // A: 256 rows x 32k = 16KB
                const int o = i * 8192 + tid * 16;
                const int r = o >> 6;
                const int gg = ((o >> 4) & 3) ^ ((r >> 1) & 3);
                gload16(Lb + (long)r * Dd + kk + gg * 8, stA + db * 16384 + o);
            }
            {                                  // B: 128 rows x 32k = 8KB
                const int o = tid * 16;
                const int c = o >> 6;
                const int gg = ((o >> 4) & 3) ^ ((c >> 1) & 3);
                gload16(Wsl + (long)c * Dd + kk + gg * 8, stB + db * 8192 + o);
            }
        };

        stage0(0, 0);
        __syncthreads();
        for (int t = 0; t < 32; ++t) {
            const int db = t & 1;
            if (t + 1 < 32) stage0(db ^ 1, t + 1);
            bf16x8 af[4], bfr[4];
            #pragma unroll
            for (int fm = 0; fm < 4; ++fm) {
                const int r = rm * 64 + fm * 16 + lr;
                af[fm] = *(const bf16x8*)(stA + db * 16384 + r * 64 + ((g ^ ((r >> 1) & 3)) << 4));
            }
            #pragma unroll
            for (int fn = 0; fn < 4; ++fn) {
                const int c = cn * 64 + fn * 16 + lr;
                bfr[fn] = *(const bf16x8*)(stB + db * 8192 + c * 64 + ((g ^ ((c >> 1) & 3)) << 4));
            }
            #pragma unroll
            for (int fm = 0; fm < 4; ++fm)
                #pragma unroll
                for (int fn = 0; fn < 4; ++fn)
                    acc[fm][fn] = __builtin_amdgcn_mfma_f32_16x16x32_bf16(af[fm], bfr[fn], acc[fm][fn], 0, 0, 0);
            __syncthreads();
        }
        // epilogue: rows n = rm*64+fm*16+g*4+rg, cols c = cn*64+fn*16+lr; +b1; store sY[c][n] swizzled
        #pragma unroll
        for (int fm = 0; fm < 4; ++fm)
            #pragma unroll
            for (int fn = 0; fn < 4; ++fn) {
                const int c = cn * 64 + fn * 16 + lr;
                const int n0 = rm * 64 + fm * 16 + g * 4;
                const float bv = bsl[c];
                u16x4 v;
                #pragma unroll
                for (int rg = 0; rg < 4; ++rg) v[rg] = bfb(acc[fm][fn][rg] + bv);
                *(u16x4*)((char*)sY + c * 512 + ((n0 * 2) ^ ((c & 7) << 4))) = v;
            }
    }

    // preload A fragments af[fm][ks] (128 VGPR), reused for both graph multiplies
    const int wm = w >> 1, wn = w & 1;
    bf16x8 afh[4][8];
    #pragma unroll
    for (int fm = 0; fm < 4; ++fm) {
        const int r = wm * 64 + fm * 16 + lr;
        #pragma unroll
        for (int ks = 0; ks < 8; ++ks)
            afh[fm][ks] = *(const bf16x8*)(Ab + (long)r * Nn_ + ks * 32 + g * 8);
    }

    __syncthreads();   // sY complete (and staging region now dead -> sZ writable after mult1)

    // ======== phase 1: Z1 = gelu(A @ Y1slice) ========
    f32x4 acc[4][4] = {};
    #pragma unroll
    for (int ks = 0; ks < 8; ++ks) {
        bf16x8 bfr[4];
        #pragma unroll
        for (int fn = 0; fn < 4; ++fn) {
            const int c = wn * 64 + fn * 16 + lr;
            const int kb = (ks * 64 + g * 16) ^ ((c & 7) << 4);
            bfr[fn] = *(const bf16x8*)((const char*)sY + c * 512 + kb);
        }
        #pragma unroll
        for (int fm = 0; fm < 4; ++fm)
            #pragma unroll
            for (int fn = 0; fn < 4; ++fn)
                acc[fm][fn] = __builtin_amdgcn_mfma_f32_16x16x32_bf16(afh[fm][ks], bfr[fn], acc[fm][fn], 0, 0, 0);
    }
    // gelu + swizzled transpose-store into sZ[c][r]
    #pragma unroll
    for (int fm = 0; fm < 4; ++fm)
        #pragma unroll
        for (int fn = 0; fn < 4; ++fn) {
            const int c = wn * 64 + fn * 16 + lr;
            const int r0 = wm * 64 + fm * 16 + g * 4;
            u16x4 v;
            #pragma unroll
            for (int rg = 0; rg < 4; ++rg) v[rg] = bfb(gelu_f(acc[fm][fn][rg]));
            *(u16x4*)((char*)sZ + c * 512 + ((r0 * 2) ^ ((c & 7) << 4))) = v;
            acc[fm][fn] = f32x4{0.f, 0.f, 0.f, 0.f};
        }
    __syncthreads();

    // ======== phase 2: AZ = A @ Z1 ========
    #pragma unroll
    for (int ks = 0; ks < 8; ++ks) {
        bf16x8 bfr[4];
        #pragma unroll
        for (int fn = 0; fn < 4; ++fn) {
            const int c = wn * 64 + fn * 16 + lr;
            const int kb = (ks * 64 + g * 16) ^ ((c & 7) << 4);
            bfr[fn] = *(const bf16x8*)((const char*)sZ + c * 512 + kb);
        }
        #pragma unroll
        for (int fm = 0; fm < 4; ++fm)
            #pragma unroll
            for (int fn = 0; fn < 4; ++fn)
                acc[fm][fn] = __builtin_amdgcn_mfma_f32_16x16x32_bf16(afh[fm][ks], bfr[fn], acc[fm][fn], 0, 0, 0);
    }
    u16* Ob = AZ + (long)z * Nn_ * Hh + cs * 128;
    #pragma unroll
    for (int fm = 0; fm < 4; ++fm)
        #pragma unroll
        for (int fn = 0; fn < 4; ++fn)
            #pragma unroll
            for (int rg = 0; rg < 4; ++rg) {
                const int r = wm * 64 + fm * 16 + g * 4 + rg;
                const int c = wn * 64 + fn * 16 + lr;
                Ob[(long)r * Hh + c] = bfb(acc[fm][fn][rg]);
            }
}

// ---------------- d2 gram via split-bf16 (hi*hi + hi*lo + lo*hi), symmetric-triangle + XCD swizzle ----
__global__ __launch_bounds__(512) void d2mm_k(
    const u16* __restrict__ HL, const float* __restrict__ sq, float* __restrict__ d2)
{
    __shared__ __align__(16) u16 sm[2][4][128 * 32];  // [dbuf][Ahi,Alo,Bhi,Blo]
    const int tid = threadIdx.x;
    const int l = tid & 63, w = tid >> 6;     // 8 waves
    const int wm = w >> 2, wn = w & 3;        // 2x4

    const int lid = blockIdx.x;            // 0..191
    const int xcd = lid & 7, q = lid >> 3; // q 0..23
    const int j   = q % 3;                 // triangle tile: 0=(0,0) 1=(0,128) 2=(128,128)
    const int z   = (q / 3) * 8 + xcd;     // batch, bijective over [0,64)
    const int bm  = (j == 2) ? 128 : 0;
    const int bn  = (j == 0) ? 0 : 128;

    const u16* Hb = HL + (long)z * Nn_ * 2048;

    f32x4 acc[4][2] = {};

    auto stage = [&](int db, int t) {
        const long kk = (long)t << 5;
        const int o = tid * 16;
        const int r = o >> 6;
        const int g = ((o >> 4) & 3) ^ ((r >> 1) & 3);
        const long ka = kk + g * 8;
        gload16(Hb + (long)(bm + r) * 2048 + ka,        (char*)&sm[db][0][0] + o);
        gload16(Hb + (long)(bm + r) * 2048 + 1024 + ka, (char*)&sm[db][1][0] + o);
        gload16(Hb + (long)(bn + r) * 2048 + ka,        (char*)&sm[db][2][0] + o);
        gload16(Hb + (long)(bn + r) * 2048 + 1024 + ka, (char*)&sm[db][3][0] + o);
    };

    stage(0, 0);
    __syncthreads();
    for (int t = 0; t < 32; ++t) {
        const int db = t & 1;
        if (t + 1 < 32) stage(db ^ 1, t + 1);
        const int lr = l & 15, g = l >> 4;
        bf16x8 ah[4], al[4], bh[2], bl[2];
        #pragma unroll
        for (int fm = 0; fm < 4; ++fm) {
            const int r = wm * 64 + fm * 16 + lr;
            const int off = r * 64 + ((g ^ ((r >> 1) & 3)) << 4);
            ah[fm] = *(const bf16x8*)((const char*)&sm[db][0][0] + off);
            al[fm] = *(const bf16x8*)((const char*)&sm[db][1][0] + off);
        }
        #pragma unroll
        for (int fn = 0; fn < 2; ++fn) {
            const int r = wn * 32 + fn * 16 + lr;
            const int off = r * 64 + ((g ^ ((r >> 1) & 3)) << 4);
            bh[fn] = *(const bf16x8*)((const char*)&sm[db][2][0] + off);
            bl[fn] = *(const bf16x8*)((const char*)&sm[db][3][0] + off);
        }
        #pragma unroll
        for (int fm = 0; fm < 4; ++fm)
            #pragma unroll
            for (int fn = 0; fn < 2; ++fn) {
                acc[fm][fn] = __builtin_amdgcn_mfma_f32_16x16x32_bf16(ah[fm], bh[fn], acc[fm][fn], 0, 0, 0);
                acc[fm][fn] = __builtin_amdgcn_mfma_f32_16x16x32_bf16(ah[fm], bl[fn], acc[fm][fn], 0, 0, 0);
                acc[fm][fn] = __builtin_amdgcn_mfma_f32_16x16x32_bf16(al[fm], bh[fn], acc[fm][fn], 0, 0, 0);
            }
        __syncthreads();
    }

    const int lr = l & 15, lg = l >> 4;
    const float* sqb = sq + z * Nn_;
    float* ob = d2 + (long)z * Nn_ * Nn_;
    #pragma unroll
    for (int fm = 0; fm < 4; ++fm)
        #pragma unroll
        for (int fn = 0; fn < 2; ++fn)
            #pragma unroll
            for (int rg = 0; rg < 4; ++rg) {
                const int gm = bm + wm * 64 + fm * 16 + lg * 4 + rg;
                const int gc = bn + wn * 32 + fn * 16 + lr;
                float v = sqb[gm] + sqb[gc] - 2.0f * acc[fm][fn][rg];
                if (gm == gc) v = INFINITY;
                ob[(long)gm * Nn_ + gc] = v;
                if (j == 1) ob[(long)gc * Nn_ + gm] = v;   // mirror (symmetric), gm<128<=gc
            }
}

// ---------------- zero-fill ----------------
__global__ __launch_bounds__(256) void clear_k(float4* __restrict__ p)
{
    p[(long)blockIdx.x * 256 + threadIdx.x] = make_float4(0.f, 0.f, 0.f, 0.f);
}

// ---------------- fused prep, WAVE-PER-ROW: tokens -> hilo + sq + LN1(b0) ----------------
__global__ __launch_bounds__(256) void prep_k(const float* __restrict__ in, u16* __restrict__ hilo,
    float* __restrict__ sq, u16* __restrict__ lnout,
    const float* __restrict__ g, const float* __restrict__ bvec)
{
    const int w = threadIdx.x >> 6, lane = threadIdx.x & 63;
    const long row = (long)blockIdx.x * 4 + w;
    const long base = row * Dd;

    float xs[16];
    #pragma unroll
    for (int c = 0; c < 4; ++c) {
        const int idx = c * 256 + lane * 4;
        const float4 v = *(const float4*)&in[base + idx];
        xs[c*4+0] = v.x; xs[c*4+1] = v.y; xs[c*4+2] = v.z; xs[c*4+3] = v.w;
        u16x4 hi, lo;
        #pragma unroll
        for (int j = 0; j < 4; ++j) {
            hi[j] = bfb(xs[c*4+j]);
            lo[j] = bfb(xs[c*4+j] - fromb(hi[j]));
        }
        *(u16x4*)&hilo[row * 2048 + idx]        = hi;
        *(u16x4*)&hilo[row * 2048 + 1024 + idx] = lo;
    }

    float s = 0.f, s2 = 0.f;
    #pragma unroll
    for (int i = 0; i < 16; ++i) { s += xs[i]; s2 += xs[i] * xs[i]; }
    #pragma unroll
    for (int o = 32; o > 0; o >>= 1) { s += __shfl_xor(s, o); s2 += __shfl_xor(s2, o); }
    if (lane == 0) sq[row] = s2;
    const float mean = s * (1.0f / Dd);
    const float rstd = rsqrtf(s2 * (1.0f / Dd) - mean * mean + LN_EPS);

    #pragma unroll
    for (int c = 0; c < 4; ++c) {
        const int idx = c * 256 + lane * 4;
        const float4 gv = *(const float4*)&g[idx];
        const float4 bv = *(const float4*)&bvec[idx];
        const float gs[4] = {gv.x, gv.y, gv.z, gv.w};
        const float bs[4] = {bv.x, bv.y, bv.z, bv.w};
        u16x4 ov;
        #pragma unroll
        for (int j = 0; j < 4; ++j) ov[j] = bfb((xs[c*4+j] - mean) * rstd * gs[j] + bs[j]);
        *(u16x4*)&lnout[base + idx] = ov;
    }
}

// ---------------- weight transpose-convert: in [R][C] f32 -> out [C][R] bf16, batched ----------------
__global__ __launch_bounds__(256) void transw_k(const float* __restrict__ in, u16* __restrict__ out,
                                                int R, int C, long sIn, long sOut)
{
    __shared__ u16 t[32][33];
    const int z = blockIdx.z;
    const float* ib = in + (long)z * sIn;
    u16* ob = out + (long)z * sOut;
    const int r0 = blockIdx.y * 32, c0 = blockIdx.x * 32;
    const int tr = threadIdx.x >> 3, tc4 = (threadIdx.x & 7) * 4;
    const float* p = ib + (long)(r0 + tr) * C + c0 + tc4;
    #pragma unroll
    for (int j = 0; j < 4; ++j) t[tr][tc4 + j] = bfb(p[j]);
    __syncthreads();
    u16* q = ob + (long)(c0 + tr) * R + r0 + tc4;
    #pragma unroll
    for (int j = 0; j < 4; ++j) q[j] = t[tc4 + j][tr];
}

// ---------------- classifier weight transpose: Wc [1024][1000] f32 -> WcT [1000][1024] f32 ----------------
__global__ __launch_bounds__(256) void transc_k(const float* __restrict__ Wc, float* __restrict__ WcT)
{
    __shared__ float t[32][33];
    const int r0 = blockIdx.y * 32, c0 = blockIdx.x * 32;
    const int tr = threadIdx.x >> 3, tc4 = (threadIdx.x & 7) * 4;
    #pragma unroll
    for (int j = 0; j < 4; ++j) {
        const int c = c0 + tc4 + j;
        t[tr][tc4 + j] = (c < NC) ? Wc[(long)(r0 + tr) * NC + c] : 0.f;
    }
    __syncthreads();
    const int oc = c0 + tr;
    if (oc < NC) {
        #pragma unroll
        for (int j = 0; j < 4; ++j)
            WcT[(long)oc * Dd + r0 + tc4 + j] = t[tc4 + j][tr];
    }
}

// ---------------- fused residual + double-LN, WAVE-PER-ROW ----------------
template<int LAST, int XF32>
__global__ __launch_bounds__(256) void ln2fr_k(const u16* __restrict__ hsrc,
    const void* __restrict__ xinv, u16* __restrict__ xout, u16* __restrict__ lnout,
    const float* __restrict__ g2, const float* __restrict__ be2,
    const float* __restrict__ gn, const float* __restrict__ bn)
{
    const int w = threadIdx.x >> 6, lane = threadIdx.x & 63;
    const long row = (long)blockIdx.x * 4 + w;
    const long base = row * Dd;

    float xs[16];
    #pragma unroll
    for (int c = 0; c < 4; ++c) {
        const int idx = c * 256 + lane * 4;
        const u16x4 hv = *(const u16x4*)&hsrc[base + idx];
        if constexpr (XF32) {
            const float4 xv = *(const float4*)&((const float*)xinv)[base + idx];
            xs[c*4+0] = xv.x + fromb(hv[0]);
            xs[c*4+1] = xv.y + fromb(hv[1]);
            xs[c*4+2] = xv.z + fromb(hv[2]);
            xs[c*4+3] = xv.w + fromb(hv[3]);
        } else {
            const u16x4 xv = *(const u16x4*)&((const u16*)xinv)[base + idx];
            #pragma unroll
            for (int j = 0; j < 4; ++j) xs[c*4+j] = fromb(xv[j]) + fromb(hv[j]);
        }
    }

    {
        float s = 0.f, s2 = 0.f;
        #pragma unroll
        for (int i = 0; i < 16; ++i) { s += xs[i]; s2 += xs[i] * xs[i]; }
        #pragma unroll
        for (int o = 32; o > 0; o >>= 1) { s += __shfl_xor(s, o); s2 += __shfl_xor(s2, o); }
        const float mean = s * (1.0f / Dd);
        const float rstd = rsqrtf(s2 * (1.0f / Dd) - mean * mean + LN_EPS);
        #pragma unroll
        for (int c = 0; c < 4; ++c) {
            const int idx = c * 256 + lane * 4;
            const float4 gv = *(const float4*)&g2[idx];
            const float4 bv = *(const float4*)&be2[idx];
            const float gs[4] = {gv.x, gv.y, gv.z, gv.w};
            const float bs[4] = {bv.x, bv.y, bv.z, bv.w};
            #pragma unroll
            for (int j = 0; j < 4; ++j)
                xs[c*4+j] = xs[c*4+j] + gelu_f((xs[c*4+j] - mean) * rstd * gs[j] + bs[j]);
        }
    }

    float s = 0.f, s2 = 0.f;
    #pragma unroll
    for (int i = 0; i < 16; ++i) { s += xs[i]; s2 += xs[i] * xs[i]; }
    #pragma unroll
    for (int o = 32; o > 0; o >>= 1) { s += __shfl_xor(s, o); s2 += __shfl_xor(s2, o); }
    const float mean = s * (1.0f / Dd);
    const float rstd = rsqrtf(s2 * (1.0f / Dd) - mean * mean + LN_EPS);
    #pragma unroll
    for (int c = 0; c < 4; ++c) {
        const int idx = c * 256 + lane * 4;
        const float4 gv = *(const float4*)&gn[idx];
        const float4 bv = *(const float4*)&bn[idx];
        const float gs[4] = {gv.x, gv.y, gv.z, gv.w};
        const float bs[4] = {bv.x, bv.y, bv.z, bv.w};
        u16x4 ov;
        if constexpr (LAST) {
            #pragma unroll
            for (int j = 0; j < 4; ++j) ov[j] = bfb(gelu_f((xs[c*4+j] - mean) * rstd * gs[j] + bs[j]));
        } else {
            u16x4 xo;
            #pragma unroll
            for (int j = 0; j < 4; ++j) xo[j] = bfb(xs[c*4+j]);
            *(u16x4*)&xout[base + idx] = xo;
            #pragma unroll
            for (int j = 0; j < 4; ++j) ov[j] = bfb((xs[c*4+j] - mean) * rstd * gs[j] + bs[j]);
        }
        *(u16x4*)&lnout[base + idx] = ov;
    }
}

__global__ __launch_bounds__(256) void topk_k(const float* __restrict__ d2, float* __restrict__ Aout,
                                              const int* __restrict__ kptr)
{
    const int k = *kptr;
    const int wid = threadIdx.x >> 6, lane = threadIdx.x & 63;
    const long row = (long)blockIdx.x * 4 + wid;
    const long b = row >> 8;
    const int  i = (int)(row & 255);
    const float* dr = d2 + row * Nn_;
    float v[4];
    bool sel[4] = {false, false, false, false};
    #pragma unroll
    for (int c = 0; c < 4; ++c) v[c] = dr[lane + 64 * c];
    for (int it = 0; it < k; ++it) {
        float bv = INFINITY; int bi = 1 << 20;
        #pragma unroll
        for (int c = 0; c < 4; ++c) {
            const int idx = lane + 64 * c;
            if (!sel[c] && (v[c] < bv || (v[c] == bv && idx < bi))) { bv = v[c]; bi = idx; }
        }
        #pragma unroll
        for (int o = 32; o > 0; o >>= 1) {
            float ov = __shfl_xor(bv, o); int oi = __shfl_xor(bi, o);
            if (ov < bv || (ov == bv && oi < bi)) { bv = ov; bi = oi; }
        }
        #pragma unroll
        for (int c = 0; c < 4; ++c) if (lane + 64 * c == bi) sel[c] = true;
        if (lane == 0) {
            Aout[(b * Nn_ + i) * Nn_ + bi] = 1.0f;
            Aout[(b * Nn_ + bi) * Nn_ + i] = 1.0f;
        }
    }
    if (lane == 0) Aout[(b * Nn_ + i) * Nn_ + i] = 1.0f;
}

__global__ __launch_bounds__(256) void deg_k(const float* __restrict__ A, float* __restrict__ dinv)
{
    const int wid = threadIdx.x >> 6, lane = threadIdx.x & 63;
    const long row = (long)blockIdx.x * 4 + wid;
    const float* ar = A + row * Nn_;
    float s = 0.f;
    #pragma unroll
    for (int c = 0; c < 4; ++c) s += ar[lane + 64 * c];
    #pragma unroll
    for (int o = 32; o > 0; o >>= 1) s += __shfl_down(s, o);
    if (lane == 0) dinv[row] = rsqrtf(s);
}

// fused: Ahat bf16 = A*di*dj  AND  rsA[row] = rowsum(Ahat) in f32. One wave per row.
__global__ __launch_bounds__(256) void scalebf2_k(const float* __restrict__ A, const float* __restrict__ dinv,
                                                  u16* __restrict__ out, float* __restrict__ rsA)
{
    const int wid = threadIdx.x >> 6, lane = threadIdx.x & 63;
    const long row = (long)blockIdx.x * 4 + wid;
    const long b = row >> 8;
    const float di = dinv[row];
    const int j0 = lane * 4;
    const float4 dj = *(const float4*)&dinv[b * Nn_ + j0];
    const float4 a = *(const float4*)&A[row * Nn_ + j0];
    const float v0 = a.x * di * dj.x, v1 = a.y * di * dj.y, v2 = a.z * di * dj.z, v3 = a.w * di * dj.w;
    u16x4 o = { bfb(v0), bfb(v1), bfb(v2), bfb(v3) };
    *(u16x4*)&out[row * Nn_ + j0] = o;
    float s = v0 + v1 + v2 + v3;
    #pragma unroll
    for (int off = 32; off > 0; off >>= 1) s += __shfl_down(s, off);
    if (lane == 0) rsA[row] = s;
}

// mean-pool over nodes, bf16 input
__global__ __launch_bounds__(256) void poolb_k(const u16* __restrict__ y, float* __restrict__ pooled)
{
    const int d = blockIdx.x * 256 + threadIdx.x;
    const int b = blockIdx.y;
    const u16* yb = y + (long)b * Nn_ * Dd + d;
    float s = 0.f;
    #pragma unroll 4
    for (int n = 0; n < Nn_; ++n) s += fromb(yb[(long)n * Dd]);
    pooled[b * Dd + d] = s * (1.0f / Nn_);
}

// one wave per (batch, class) logit
__global__ __launch_bounds__(256) void cls2_k(const float* __restrict__ pooled, const float* __restrict__ WcT,
    const float* __restrict__ bc, float* __restrict__ out)
{
    const int w = threadIdx.x >> 6, lane = threadIdx.x & 63;
    const int c = blockIdx.x * 4 + w;
    const int b = blockIdx.y;
    const float* wr = WcT + (long)c * Dd;
    const float* p  = pooled + (long)b * Dd;
    float s = 0.f;
    #pragma unroll
    for (int it = 0; it < 4; ++it) {
        const float4 wv = *(const float4*)&wr[it * 256 + lane * 4];
        const float4 pv = *(const float4*)&p[it * 256 + lane * 4];
        s += wv.x * pv.x + wv.y * pv.y + wv.z * pv.z + wv.w * pv.w;
    }
    #pragma unroll
    for (int o = 32; o > 0; o >>= 1) s += __shfl_down(s, o);
    if (lane == 0) out[(long)b * NC + c] = s + bc[c];
}

extern "C" void kernel_launch(void* const* d_in, const int* in_sizes, int n_in,
                              void* d_out, int out_size, void* d_ws, size_t ws_size,
                              hipStream_t stream)
{
    const float* tokens = (const float*)d_in[0];
    const float* W1  = (const float*)d_in[1];
    const float* b1  = (const float*)d_in[2];
    const float* W2  = (const float*)d_in[3];
    const float* b2  = (const float*)d_in[4];
    const float* g1  = (const float*)d_in[5];
    const float* be1 = (const float*)d_in[6];
    const float* g2  = (const float*)d_in[7];
    const float* be2 = (const float*)d_in[8];
    const float* gr  = (const float*)d_in[9];
    const float* br  = (const float*)d_in[10];
    const float* Wc  = (const float*)d_in[11];
    const float* bc  = (const float*)d_in[12];
    const int*   kptr = (const int*)d_in[13];

    constexpr long SZ_XD = (long)Bb * Nn_ * Dd;   // 16.78M elems
    constexpr long SZ_A  = (long)Bb * Nn_ * Nn_;  //  4.19M elems

    // workspace carve (~155 MB; <= round-1-proven 218.5 MB)
    char* wp = (char*)d_ws;
    u16*   xbf    = (u16*)wp;   wp += SZ_XD * 2;   // residual trunk bf16 (kNN phase: AmatF f32)
    u16*   hbuf   = (u16*)wp;   wp += SZ_XD * 2;   // lin2' output h bf16 (kNN phase: d2f f32)
    u16*   bufA   = (u16*)wp;   wp += SZ_XD * 2;   // hilo lower | AZ | readout bf16
    u16*   bufB   = (u16*)wp;   wp += SZ_XD * 2;   // hilo upper (kNN only)
    u16*   bufC   = (u16*)wp;   wp += SZ_XD * 2;   // LN1 output bf16 (ayy2 A-operand)
    u16*   AmatBF = (u16*)wp;   wp += SZ_A * 2;
    u16*   W1t    = (u16*)wp;   wp += 2L * Dd * Hh * 2;
    u16*   W2t    = (u16*)wp;   wp += 2L * Hh * Dd * 2;
    float* WcT    = (float*)wp; wp += (long)NC * Dd * 4;
    float* sq     = (float*)wp; wp += (long)Bb * Nn_ * 4;
    float* dinv   = (float*)wp; wp += (long)Bb * Nn_ * 4;
    float* rsA    = (float*)wp; wp += (long)Bb * Nn_ * 4;
    float* pooled = (float*)wp; wp += (long)Bb * Dd * 4;

    // phase aliases (lifetimes disjoint):
    u16*   hilo  = bufA;            // [B*N][2048] bf16 hi|lo spans bufA+bufB, dead after d2mm
    float* d2f   = (float*)hbuf;    // f32 distances, dead after topk; h first written iter0 lin2'
    float* AmatF = (float*)xbf;     // f32 adjacency, dead after scalebf2; x first written iter0 ln2fr
    u16*   robuf = bufA;            // readout bf16 (AZ dead after lin2' of last iter)

    const dim3 blk(256);
    const dim3 blk8(512);

    // ---- fused prep (wave-per-row): tokens -> hilo + sq + LN1(block0) in ONE pass ----
    prep_k<<<Bb * Nn_ / 4, blk, 0, stream>>>(tokens, hilo, sq, bufC, g1, be1);

    // ---- kNN adjacency: triangle + XCD-swizzled d2, 8-wave blocks ----
    d2mm_k<<<192, blk8, 0, stream>>>(hilo, sq, d2f);
    clear_k<<<(int)(SZ_A / 4 / 256), blk, 0, stream>>>((float4*)AmatF);
    topk_k<<<Bb * Nn_ / 4, blk, 0, stream>>>(d2f, AmatF, kptr);
    deg_k<<<Bb * Nn_ / 4, blk, 0, stream>>>(AmatF, dinv);
    scalebf2_k<<<Bb * Nn_ / 4, blk, 0, stream>>>(AmatF, dinv, AmatBF, rsA);

    // ---- weight transposes ----
    transw_k<<<dim3(Hh / 32, Dd / 32, 2), blk, 0, stream>>>(W1, W1t, Dd, Hh, (long)Dd * Hh, (long)Hh * Dd);
    transw_k<<<dim3(Dd / 32, Hh / 32, 2), blk, 0, stream>>>(W2, W2t, Hh, Dd, (long)Hh * Dd, (long)Dd * Hh);
    transc_k<<<dim3(32, Dd / 32), blk, 0, stream>>>(Wc, WcT);

    // ---- GraphBlocks ----
    for (int i = 0; i < 2; ++i) {
        // fused lin1 + AY double-multiply: AZ = Ahat @ gelu(Ahat @ (LN1@W1+b1))   (256 blocks)
        ayy2_k<<<256, blk8, 0, stream>>>(AmatBF, bufC, W1t + (long)i * Hh * Dd, b1 + (long)i * Hh, bufA);
        // lin2': h[16384][1024] = AZ @ W2 + rsA*b2   (nx=8, ny=128, nz=1 -> 1024 blocks)
        mgemm_k<EP_SBIAS_BF><<<1024, blk8, 0, stream>>>(
            bufA, W2t + (long)i * Dd * Hh, hbuf, b2 + i * Dd, rsA,
            Bb * Nn_, Dd, Hh, 0, 0, 0, 3, 7, 0);
        // fused residual + double-LN (wave-per-row)
        if (i == 0)
            ln2fr_k<0, 1><<<Bb * Nn_ / 4, blk, 0, stream>>>(hbuf, tokens, xbf, bufC,
                g2, be2, g1 + Dd, be1 + Dd);
        else
            ln2fr_k<1, 0><<<Bb * Nn_ / 4, blk, 0, stream>>>(hbuf, xbf, nullptr, robuf,
                g2 + Dd, be2 + Dd, gr, br);
    }

    // ---- pool + classifier ----
    poolb_k<<<dim3(Dd / 256, Bb), blk, 0, stream>>>(robuf, pooled);
    cls2_k<<<dim3(NC / 4, Bb), blk, 0, stream>>>(pooled, WcT, bc, (float*)d_out);
}

// Round 16
// 347.134 us; speedup vs baseline: 1.0559x; 1.0029x over previous
//
#include <hip/hip_runtime.h>
#include <hip/hip_bf16.h>
#include <math.h>

constexpr int Bb  = 64;    // batch
constexpr int Nn_ = 256;   // nodes
constexpr int Dd  = 1024;  // feature dim
constexpr int Hh  = 512;   // hidden
constexpr int NC  = 1000;  // classes
constexpr float LN_EPS = 1e-5f;

#define DEV __device__ __forceinline__

typedef unsigned short u16;
typedef __attribute__((ext_vector_type(8))) short bf16x8;   // 8 bf16 = 4 VGPR
typedef __attribute__((ext_vector_type(4))) float f32x4;
typedef __attribute__((ext_vector_type(4))) unsigned short u16x4;

// fast erf: Abramowitz-Stegun 7.1.26 (abs err < 1.5e-7) with HW rcp + HW exp.
DEV float erf_fast(float x) {
    const float ax = fabsf(x);
    const float t = __builtin_amdgcn_rcpf(fmaf(0.3275911f, ax, 1.0f));
    const float y = t * (0.254829592f + t * (-0.284496736f + t * (1.421413741f +
                    t * (-1.453152027f + t * 1.061405429f))));
    const float r = 1.0f - y * __expf(-ax * ax);
    return copysignf(r, x);
}
DEV float gelu_f(float x) { return 0.5f * x * (1.0f + erf_fast(x * 0.70710678118654752f)); }
DEV u16 bfb(float x) { __hip_bfloat16 h = __float2bfloat16(x); u16 u; __builtin_memcpy(&u, &h, 2); return u; }
DEV float fromb(u16 u) { unsigned int w = (unsigned int)u << 16; float f; __builtin_memcpy(&f, &w, 4); return f; }

// async global->LDS, 16B per lane
DEV void gload16(const void* g, void* l) {
    __builtin_amdgcn_global_load_lds(
        (const __attribute__((address_space(1))) void*)(uintptr_t)g,
        (__attribute__((address_space(3))) void*)(uintptr_t)l, 16, 0, 0);
}

// ---------------- bf16 MFMA GEMM: C = epi(A @ B), A [M,K] rm bf16, Bt [N,K] rm bf16 ----------------
// 128x128 tile, BK=32, 8 waves (2x4, per-wave 64x32), 16x16x32 MFMA, XOR slot-swizzle (rule #21).
// XCD-aware 1D grid (T1, A/B-proven round 11: -33 us). Used for lin2' only now.
enum { EP_SBIAS_BF = 3 };

template<int EPI>
__global__ __launch_bounds__(512) void mgemm_k(
    const u16* __restrict__ Ag, const u16* __restrict__ Bg, void* __restrict__ Cg,
    const float* __restrict__ bias, const float* __restrict__ rsA,
    int M, int Nc, int K, long sA, long sB, long sC,
    int lognx, int logny, int lognz)
{
    __shared__ __align__(16) u16 sm[2][2][128 * 32];
    const int tid = threadIdx.x;
    const int l = tid & 63, w = tid >> 6;   // 8 waves
    const int wm = w >> 2, wn = w & 3;      // 2x4

    // XCD-aware decode (bijective; all dims are powers of 2)
    const int lid = blockIdx.x;
    const int xcd = lid & 7, idx = lid >> 3;
    int bxi, byi, z;
    if (lognz == 0) {                 // weight GEMM: group over x, spread y across XCDs
        bxi = idx & ((1 << lognx) - 1);
        byi = (xcd << (logny - 3)) | (idx >> lognx);
        z = 0;
    } else {
        bxi = idx & ((1 << lognx) - 1);
        byi = (idx >> lognx) & ((1 << logny) - 1);
        z = (xcd << (lognz - 3)) | (idx >> (lognx + logny));
    }
    const int bm = byi * 128, bn = bxi * 128;

    const u16* Ab  = Ag + (long)z * sA;
    const u16* Bbp = Bg + (long)z * sB;

    f32x4 acc[4][2] = {};
    const int nt = K >> 5;

    auto stage = [&](int db, int t) {
        const long kk = (long)t << 5;
        const int o = tid * 16;                         // 512 lanes x 16B = full 8KB operand tile
        const int r = o >> 6;                           // tile row 0..127
        const int g = ((o >> 4) & 3) ^ ((r >> 1) & 3);  // inverse-swizzled k-slot
        gload16(Ab  + (long)(bm + r) * K + kk + g * 8, (char*)&sm[db][0][0] + o);
        gload16(Bbp + (long)(bn + r) * K + kk + g * 8, (char*)&sm[db][1][0] + o);
    };

    stage(0, 0);
    __syncthreads();
    for (int t = 0; t < nt; ++t) {
        const int db = t & 1;
        if (t + 1 < nt) stage(db ^ 1, t + 1);
        const int lr = l & 15, g = l >> 4;
        bf16x8 af[4], bfr[2];
        #pragma unroll
        for (int fm = 0; fm < 4; ++fm) {
            const int r = wm * 64 + fm * 16 + lr;
            af[fm] = *(const bf16x8*)((const char*)&sm[db][0][0] + r * 64 + ((g ^ ((r >> 1) & 3)) << 4));
        }
        #pragma unroll
        for (int fn = 0; fn < 2; ++fn) {
            const int r = wn * 32 + fn * 16 + lr;
            bfr[fn] = *(const bf16x8*)((const char*)&sm[db][1][0] + r * 64 + ((g ^ ((r >> 1) & 3)) << 4));
        }
        #pragma unroll
        for (int fm = 0; fm < 4; ++fm)
            #pragma unroll
            for (int fn = 0; fn < 2; ++fn)
                acc[fm][fn] = __builtin_amdgcn_mfma_f32_16x16x32_bf16(af[fm], bfr[fn], acc[fm][fn], 0, 0, 0);
        __syncthreads();
    }

    // epilogue: C/D layout col=lane&15, row=(lane>>4)*4+reg (m89-verified)
    const int lr = l & 15, lg = l >> 4;
    u16* Cb = (u16*)Cg;
    #pragma unroll
    for (int fm = 0; fm < 4; ++fm)
        #pragma unroll
        for (int fn = 0; fn < 2; ++fn) {
            const int gc = bn + wn * 32 + fn * 16 + lr;
            const float bv = bias[gc];
            #pragma unroll
            for (int rg = 0; rg < 4; ++rg) {
                const int gm = bm + wm * 64 + fm * 16 + lg * 4 + rg;
                Cb[(long)gm * Nc + gc] = bfb(acc[fm][fn][rg] + rsA[gm] * bv);
            }
        }
}

// ---------------- fused lin1 + graph double-multiply:
// AZ = Ahat @ gelu(Ahat @ (LN1 @ W1slice + b1)), column-sliced. One block per (batch z, 128-col slice).
// Phase 0: pipelined K=1024 GEMM Y1slice = LN1@W1sl + b1, output transposed-swizzled DIRECTLY into sY.
// Phase 1/2: A-frags preloaded in 128 VGPR, reused both multiplies; Z1 LDS-only.
// amdgpu_waves_per_eu(2,2): LDS (128KB) pins 1 block/CU = 2 waves/EU, so the true VGPR budget is
// 512/2 = 256/wave. Without the attribute the occupancy heuristic throttled to 128 VGPR (r15 counters)
// and spilled the af[4][8] cache to scratch.
__global__ __launch_bounds__(512) __attribute__((amdgpu_waves_per_eu(2, 2))) void ayy2_k(
    const u16* __restrict__ Ahat, const u16* __restrict__ LN1, const u16* __restrict__ W1t,
    const float* __restrict__ b1, u16* __restrict__ AZ)
{
    __shared__ __align__(16) char smem[131072];
    u16* sY = (u16*)smem;                      // [128 c][256 n] swizzled, 64KB
    u16* sZ = (u16*)(smem + 65536);            // [128 c][256 r] swizzled, 64KB (phase-0: staging alias)
    char* stA = smem + 65536;                  // [2][256*32] u16, 16KB per buf (aliases sZ)
    char* stB = smem + 65536 + 32768;          // [2][128*32] u16,  8KB per buf

    const int tid = threadIdx.x;
    const int l = tid & 63, w = tid >> 6;
    const int lr = l & 15, g = l >> 4;

    const int lid = blockIdx.x;                 // 256 blocks; all 4 slices of a batch on one XCD
    const int xcd = lid & 7, idx = lid >> 3;
    const int cs = idx & 3;
    const int z  = xcd * 8 + (idx >> 2);

    const u16* Ab  = Ahat + (long)z * Nn_ * Nn_;
    const u16* Lb  = LN1 + (long)z * Nn_ * Dd;            // [256 n][1024 k]
    const u16* Wsl = W1t + (long)(cs * 128) * Dd;         // [128 c][1024 k]
    const float* bsl = b1 + cs * 128;

    // ======== phase 0: Y1slice = LN1 @ W1sl + b1 -> sY (transposed swizzled) ========
    {
        const int rm = w >> 1, cn = w & 1;    // 4x2 wave grid: 64n x 64c per wave
        f32x4 acc[4][4] = {};

        auto stage0 = [&](int db, int t) {
            const long kk = (long)t << 5;
            #pragma unroll
            for (int i = 0; i < 2; ++i) {     // A: 256 rows x 32k = 16KB
                const int o = i * 8192 + tid * 16;
                const int r = o >> 6;
                const int gg = ((o >> 4) & 3) ^ ((r >> 1) & 3);
                gload16(Lb + (long)r * Dd + kk + gg * 8, stA + db * 16384 + o);
            }
            {                                  // B: 128 rows x 32k = 8KB
                const int o = tid * 16;
                const int c = o >> 6;
                const int gg = ((o >> 4) & 3) ^ ((c >> 1) & 3);
                gload16(Wsl + (long)c * Dd + kk + gg * 8, stB + db * 8192 + o);
            }
        };

        stage0(0, 0);
        __syncthreads();
        for (int t = 0; t < 32; ++t) {
            const int db = t & 1;
            if (t + 1 < 32) stage0(db ^ 1, t + 1);
            bf16x8 af[4], bfr[4];
            #pragma unroll
            for (int fm = 0; fm < 4; ++fm) {
                const int r = rm * 64 + fm * 16 + lr;
                af[fm] = *(const bf16x8*)(stA + db * 16384 + r * 64 + ((g ^ ((r >> 1) & 3)) << 4));
            }
            #pragma unroll
            for (int fn = 0; fn < 4; ++fn) {
                const int c = cn * 64 + fn * 16 + lr;
                bfr[fn] = *(const bf16x8*)(stB + db * 8192 + c * 64 + ((g ^ ((c >> 1) & 3)) << 4));
            }
            #pragma unroll
            for (int fm = 0; fm < 4; ++fm)
                #pragma unroll
                for (int fn = 0; fn < 4; ++fn)
                    acc[fm][fn] = __builtin_amdgcn_mfma_f32_16x16x32_bf16(af[fm], bfr[fn], acc[fm][fn], 0, 0, 0);
            __syncthreads();
        }
        // epilogue: rows n = rm*64+fm*16+g*4+rg, cols c = cn*64+fn*16+lr; +b1; store sY[c][n] swizzled
        #pragma unroll
        for (int fm = 0; fm < 4; ++fm)
            #pragma unroll
            for (int fn = 0; fn < 4; ++fn) {
                const int c = cn * 64 + fn * 16 + lr;
                const int n0 = rm * 64 + fm * 16 + g * 4;
                const float bv = bsl[c];
                u16x4 v;
                #pragma unroll
                for (int rg = 0; rg < 4; ++rg) v[rg] = bfb(acc[fm][fn][rg] + bv);
                *(u16x4*)((char*)sY + c * 512 + ((n0 * 2) ^ ((c & 7) << 4))) = v;
            }
    }

    // preload A fragments af[fm][ks] (128 VGPR), reused for both graph multiplies
    const int wm = w >> 1, wn = w & 1;
    bf16x8 afh[4][8];
    #pragma unroll
    for (int fm = 0; fm < 4; ++fm) {
        const int r = wm * 64 + fm * 16 + lr;
        #pragma unroll
        for (int ks = 0; ks < 8; ++ks)
            afh[fm][ks] = *(const bf16x8*)(Ab + (long)r * Nn_ + ks * 32 + g * 8);
    }

    __syncthreads();   // sY complete (and staging region now dead -> sZ writable after mult1)

    // ======== phase 1: Z1 = gelu(A @ Y1slice) ========
    f32x4 acc[4][4] = {};
    #pragma unroll
    for (int ks = 0; ks < 8; ++ks) {
        bf16x8 bfr[4];
        #pragma unroll
        for (int fn = 0; fn < 4; ++fn) {
            const int c = wn * 64 + fn * 16 + lr;
            const int kb = (ks * 64 + g * 16) ^ ((c & 7) << 4);
            bfr[fn] = *(const bf16x8*)((const char*)sY + c * 512 + kb);
        }
        #pragma unroll
        for (int fm = 0; fm < 4; ++fm)
            #pragma unroll
            for (int fn = 0; fn < 4; ++fn)
                acc[fm][fn] = __builtin_amdgcn_mfma_f32_16x16x32_bf16(afh[fm][ks], bfr[fn], acc[fm][fn], 0, 0, 0);
    }
    // gelu + swizzled transpose-store into sZ[c][r]
    #pragma unroll
    for (int fm = 0; fm < 4; ++fm)
        #pragma unroll
        for (int fn = 0; fn < 4; ++fn) {
            const int c = wn * 64 + fn * 16 + lr;
            const int r0 = wm * 64 + fm * 16 + g * 4;
            u16x4 v;
            #pragma unroll
            for (int rg = 0; rg < 4; ++rg) v[rg] = bfb(gelu_f(acc[fm][fn][rg]));
            *(u16x4*)((char*)sZ + c * 512 + ((r0 * 2) ^ ((c & 7) << 4))) = v;
            acc[fm][fn] = f32x4{0.f, 0.f, 0.f, 0.f};
        }
    __syncthreads();

    // ======== phase 2: AZ = A @ Z1 ========
    #pragma unroll
    for (int ks = 0; ks < 8; ++ks) {
        bf16x8 bfr[4];
        #pragma unroll
        for (int fn = 0; fn < 4; ++fn) {
            const int c = wn * 64 + fn * 16 + lr;
            const int kb = (ks * 64 + g * 16) ^ ((c & 7) << 4);
            bfr[fn] = *(const bf16x8*)((const char*)sZ + c * 512 + kb);
        }
        #pragma unroll
        for (int fm = 0; fm < 4; ++fm)
            #pragma unroll
            for (int fn = 0; fn < 4; ++fn)
                acc[fm][fn] = __builtin_amdgcn_mfma_f32_16x16x32_bf16(afh[fm][ks], bfr[fn], acc[fm][fn], 0, 0, 0);
    }
    u16* Ob = AZ + (long)z * Nn_ * Hh + cs * 128;
    #pragma unroll
    for (int fm = 0; fm < 4; ++fm)
        #pragma unroll
        for (int fn = 0; fn < 4; ++fn)
            #pragma unroll
            for (int rg = 0; rg < 4; ++rg) {
                const int r = wm * 64 + fm * 16 + g * 4 + rg;
                const int c = wn * 64 + fn * 16 + lr;
                Ob[(long)r * Hh + c] = bfb(acc[fm][fn][rg]);
            }
}

// ---------------- d2 gram via split-bf16 (hi*hi + hi*lo + lo*hi), symmetric-triangle + XCD swizzle ----
__global__ __launch_bounds__(512) void d2mm_k(
    const u16* __restrict__ HL, const float* __restrict__ sq, float* __restrict__ d2)
{
    __shared__ __align__(16) u16 sm[2][4][128 * 32];  // [dbuf][Ahi,Alo,Bhi,Blo]
    const int tid = threadIdx.x;
    const int l = tid & 63, w = tid >> 6;     // 8 waves
    const int wm = w >> 2, wn = w & 3;        // 2x4

    const int lid = blockIdx.x;            // 0..191
    const int xcd = lid & 7, q = lid >> 3; // q 0..23
    const int j   = q % 3;                 // triangle tile: 0=(0,0) 1=(0,128) 2=(128,128)
    const int z   = (q / 3) * 8 + xcd;     // batch, bijective over [0,64)
    const int bm  = (j == 2) ? 128 : 0;
    const int bn  = (j == 0) ? 0 : 128;

    const u16* Hb = HL + (long)z * Nn_ * 2048;

    f32x4 acc[4][2] = {};

    auto stage = [&](int db, int t) {
        const long kk = (long)t << 5;
        const int o = tid * 16;
        const int r = o >> 6;
        const int g = ((o >> 4) & 3) ^ ((r >> 1) & 3);
        const long ka = kk + g * 8;
        gload16(Hb + (long)(bm + r) * 2048 + ka,        (char*)&sm[db][0][0] + o);
        gload16(Hb + (long)(bm + r) * 2048 + 1024 + ka, (char*)&sm[db][1][0] + o);
        gload16(Hb + (long)(bn + r) * 2048 + ka,        (char*)&sm[db][2][0] + o);
        gload16(Hb + (long)(bn + r) * 2048 + 1024 + ka, (char*)&sm[db][3][0] + o);
    };

    stage(0, 0);
    __syncthreads();
    for (int t = 0; t < 32; ++t) {
        const int db = t & 1;
        if (t + 1 < 32) stage(db ^ 1, t + 1);
        const int lr = l & 15, g = l >> 4;
        bf16x8 ah[4], al[4], bh[2], bl[2];
        #pragma unroll
        for (int fm = 0; fm < 4; ++fm) {
            const int r = wm * 64 + fm * 16 + lr;
            const int off = r * 64 + ((g ^ ((r >> 1) & 3)) << 4);
            ah[fm] = *(const bf16x8*)((const char*)&sm[db][0][0] + off);
            al[fm] = *(const bf16x8*)((const char*)&sm[db][1][0] + off);
        }
        #pragma unroll
        for (int fn = 0; fn < 2; ++fn) {
            const int r = wn * 32 + fn * 16 + lr;
            const int off = r * 64 + ((g ^ ((r >> 1) & 3)) << 4);
            bh[fn] = *(const bf16x8*)((const char*)&sm[db][2][0] + off);
            bl[fn] = *(const bf16x8*)((const char*)&sm[db][3][0] + off);
        }
        #pragma unroll
        for (int fm = 0; fm < 4; ++fm)
            #pragma unroll
            for (int fn = 0; fn < 2; ++fn) {
                acc[fm][fn] = __builtin_amdgcn_mfma_f32_16x16x32_bf16(ah[fm], bh[fn], acc[fm][fn], 0, 0, 0);
                acc[fm][fn] = __builtin_amdgcn_mfma_f32_16x16x32_bf16(ah[fm], bl[fn], acc[fm][fn], 0, 0, 0);
                acc[fm][fn] = __builtin_amdgcn_mfma_f32_16x16x32_bf16(al[fm], bh[fn], acc[fm][fn], 0, 0, 0);
            }
        __syncthreads();
    }

    const int lr = l & 15, lg = l >> 4;
    const float* sqb = sq + z * Nn_;
    float* ob = d2 + (long)z * Nn_ * Nn_;
    #pragma unroll
    for (int fm = 0; fm < 4; ++fm)
        #pragma unroll
        for (int fn = 0; fn < 2; ++fn)
            #pragma unroll
            for (int rg = 0; rg < 4; ++rg) {
                const int gm = bm + wm * 64 + fm * 16 + lg * 4 + rg;
                const int gc = bn + wn * 32 + fn * 16 + lr;
                float v = sqb[gm] + sqb[gc] - 2.0f * acc[fm][fn][rg];
                if (gm == gc) v = INFINITY;
                ob[(long)gm * Nn_ + gc] = v;
                if (j == 1) ob[(long)gc * Nn_ + gm] = v;   // mirror (symmetric), gm<128<=gc
            }
}

// ---------------- zero-fill ----------------
__global__ __launch_bounds__(256) void clear_k(float4* __restrict__ p)
{
    p[(long)blockIdx.x * 256 + threadIdx.x] = make_float4(0.f, 0.f, 0.f, 0.f);
}

// ---------------- fused prep, WAVE-PER-ROW: tokens -> hilo + sq + LN1(b0) ----------------
__global__ __launch_bounds__(256) void prep_k(const float* __restrict__ in, u16* __restrict__ hilo,
    float* __restrict__ sq, u16* __restrict__ lnout,
    const float* __restrict__ g, const float* __restrict__ bvec)
{
    const int w = threadIdx.x >> 6, lane = threadIdx.x & 63;
    const long row = (long)blockIdx.x * 4 + w;
    const long base = row * Dd;

    float xs[16];
    #pragma unroll
    for (int c = 0; c < 4; ++c) {
        const int idx = c * 256 + lane * 4;
        const float4 v = *(const float4*)&in[base + idx];
        xs[c*4+0] = v.x; xs[c*4+1] = v.y; xs[c*4+2] = v.z; xs[c*4+3] = v.w;
        u16x4 hi, lo;
        #pragma unroll
        for (int j = 0; j < 4; ++j) {
            hi[j] = bfb(xs[c*4+j]);
            lo[j] = bfb(xs[c*4+j] - fromb(hi[j]));
        }
        *(u16x4*)&hilo[row * 2048 + idx]        = hi;
        *(u16x4*)&hilo[row * 2048 + 1024 + idx] = lo;
    }

    float s = 0.f, s2 = 0.f;
    #pragma unroll
    for (int i = 0; i < 16; ++i) { s += xs[i]; s2 += xs[i] * xs[i]; }
    #pragma unroll
    for (int o = 32; o > 0; o >>= 1) { s += __shfl_xor(s, o); s2 += __shfl_xor(s2, o); }
    if (lane == 0) sq[row] = s2;
    const float mean = s * (1.0f / Dd);
    const float rstd = rsqrtf(s2 * (1.0f / Dd) - mean * mean + LN_EPS);

    #pragma unroll
    for (int c = 0; c < 4; ++c) {
        const int idx = c * 256 + lane * 4;
        const float4 gv = *(const float4*)&g[idx];
        const float4 bv = *(const float4*)&bvec[idx];
        const float gs[4] = {gv.x, gv.y, gv.z, gv.w};
        const float bs[4] = {bv.x, bv.y, bv.z, bv.w};
        u16x4 ov;
        #pragma unroll
        for (int j = 0; j < 4; ++j) ov[j] = bfb((xs[c*4+j] - mean) * rstd * gs[j] + bs[j]);
        *(u16x4*)&lnout[base + idx] = ov;
    }
}

// ---------------- weight transpose-convert: in [R][C] f32 -> out [C][R] bf16, batched ----------------
__global__ __launch_bounds__(256) void transw_k(const float* __restrict__ in, u16* __restrict__ out,
                                                int R, int C, long sIn, long sOut)
{
    __shared__ u16 t[32][33];
    const int z = blockIdx.z;
    const float* ib = in + (long)z * sIn;
    u16* ob = out + (long)z * sOut;
    const int r0 = blockIdx.y * 32, c0 = blockIdx.x * 32;
    const int tr = threadIdx.x >> 3, tc4 = (threadIdx.x & 7) * 4;
    const float* p = ib + (long)(r0 + tr) * C + c0 + tc4;
    #pragma unroll
    for (int j = 0; j < 4; ++j) t[tr][tc4 + j] = bfb(p[j]);
    __syncthreads();
    u16* q = ob + (long)(c0 + tr) * R + r0 + tc4;
    #pragma unroll
    for (int j = 0; j < 4; ++j) q[j] = t[tc4 + j][tr];
}

// ---------------- classifier weight transpose: Wc [1024][1000] f32 -> WcT [1000][1024] f32 ----------------
__global__ __launch_bounds__(256) void transc_k(const float* __restrict__ Wc, float* __restrict__ WcT)
{
    __shared__ float t[32][33];
    const int r0 = blockIdx.y * 32, c0 = blockIdx.x * 32;
    const int tr = threadIdx.x >> 3, tc4 = (threadIdx.x & 7) * 4;
    #pragma unroll
    for (int j = 0; j < 4; ++j) {
        const int c = c0 + tc4 + j;
        t[tr][tc4 + j] = (c < NC) ? Wc[(long)(r0 + tr) * NC + c] : 0.f;
    }
    __syncthreads();
    const int oc = c0 + tr;
    if (oc < NC) {
        #pragma unroll
        for (int j = 0; j < 4; ++j)
            WcT[(long)oc * Dd + r0 + tc4 + j] = t[tc4 + j][tr];
    }
}

// ---------------- fused residual + double-LN, WAVE-PER-ROW ----------------
template<int LAST, int XF32>
__global__ __launch_bounds__(256) void ln2fr_k(const u16* __restrict__ hsrc,
    const void* __restrict__ xinv, u16* __restrict__ xout, u16* __restrict__ lnout,
    const float* __restrict__ g2, const float* __restrict__ be2,
    const float* __restrict__ gn, const float* __restrict__ bn)
{
    const int w = threadIdx.x >> 6, lane = threadIdx.x & 63;
    const long row = (long)blockIdx.x * 4 + w;
    const long base = row * Dd;

    float xs[16];
    #pragma unroll
    for (int c = 0; c < 4; ++c) {
        const int idx = c * 256 + lane * 4;
        const u16x4 hv = *(const u16x4*)&hsrc[base + idx];
        if constexpr (XF32) {
            const float4 xv = *(const float4*)&((const float*)xinv)[base + idx];
            xs[c*4+0] = xv.x + fromb(hv[0]);
            xs[c*4+1] = xv.y + fromb(hv[1]);
            xs[c*4+2] = xv.z + fromb(hv[2]);
            xs[c*4+3] = xv.w + fromb(hv[3]);
        } else {
            const u16x4 xv = *(const u16x4*)&((const u16*)xinv)[base + idx];
            #pragma unroll
            for (int j = 0; j < 4; ++j) xs[c*4+j] = fromb(xv[j]) + fromb(hv[j]);
        }
    }

    {
        float s = 0.f, s2 = 0.f;
        #pragma unroll
        for (int i = 0; i < 16; ++i) { s += xs[i]; s2 += xs[i] * xs[i]; }
        #pragma unroll
        for (int o = 32; o > 0; o >>= 1) { s += __shfl_xor(s, o); s2 += __shfl_xor(s2, o); }
        const float mean = s * (1.0f / Dd);
        const float rstd = rsqrtf(s2 * (1.0f / Dd) - mean * mean + LN_EPS);
        #pragma unroll
        for (int c = 0; c < 4; ++c) {
            const int idx = c * 256 + lane * 4;
            const float4 gv = *(const float4*)&g2[idx];
            const float4 bv = *(const float4*)&be2[idx];
            const float gs[4] = {gv.x, gv.y, gv.z, gv.w};
            const float bs[4] = {bv.x, bv.y, bv.z, bv.w};
            #pragma unroll
            for (int j = 0; j < 4; ++j)
                xs[c*4+j] = xs[c*4+j] + gelu_f((xs[c*4+j] - mean) * rstd * gs[j] + bs[j]);
        }
    }

    float s = 0.f, s2 = 0.f;
    #pragma unroll
    for (int i = 0; i < 16; ++i) { s += xs[i]; s2 += xs[i] * xs[i]; }
    #pragma unroll
    for (int o = 32; o > 0; o >>= 1) { s += __shfl_xor(s, o); s2 += __shfl_xor(s2, o); }
    const float mean = s * (1.0f / Dd);
    const float rstd = rsqrtf(s2 * (1.0f / Dd) - mean * mean + LN_EPS);
    #pragma unroll
    for (int c = 0; c < 4; ++c) {
        const int idx = c * 256 + lane * 4;
        const float4 gv = *(const float4*)&gn[idx];
        const float4 bv = *(const float4*)&bn[idx];
        const float gs[4] = {gv.x, gv.y, gv.z, gv.w};
        const float bs[4] = {bv.x, bv.y, bv.z, bv.w};
        u16x4 ov;
        if constexpr (LAST) {
            #pragma unroll
            for (int j = 0; j < 4; ++j) ov[j] = bfb(gelu_f((xs[c*4+j] - mean) * rstd * gs[j] + bs[j]));
        } else {
            u16x4 xo;
            #pragma unroll
            for (int j = 0; j < 4; ++j) xo[j] = bfb(xs[c*4+j]);
            *(u16x4*)&xout[base + idx] = xo;
            #pragma unroll
            for (int j = 0; j < 4; ++j) ov[j] = bfb((xs[c*4+j] - mean) * rstd * gs[j] + bs[j]);
        }
        *(u16x4*)&lnout[base + idx] = ov;
    }
}

__global__ __launch_bounds__(256) void topk_k(const float* __restrict__ d2, float* __restrict__ Aout,
                                              const int* __restrict__ kptr)
{
    const int k = *kptr;
    const int wid = threadIdx.x >> 6, lane = threadIdx.x & 63;
    const long row = (long)blockIdx.x * 4 + wid;
    const long b = row >> 8;
    const int  i = (int)(row & 255);
    const float* dr = d2 + row * Nn_;
    float v[4];
    bool sel[4] = {false, false, false, false};
    #pragma unroll
    for (int c = 0; c < 4; ++c) v[c] = dr[lane + 64 * c];
    for (int it = 0; it < k; ++it) {
        float bv = INFINITY; int bi = 1 << 20;
        #pragma unroll
        for (int c = 0; c < 4; ++c) {
            const int idx = lane + 64 * c;
            if (!sel[c] && (v[c] < bv || (v[c] == bv && idx < bi))) { bv = v[c]; bi = idx; }
        }
        #pragma unroll
        for (int o = 32; o > 0; o >>= 1) {
            float ov = __shfl_xor(bv, o); int oi = __shfl_xor(bi, o);
            if (ov < bv || (ov == bv && oi < bi)) { bv = ov; bi = oi; }
        }
        #pragma unroll
        for (int c = 0; c < 4; ++c) if (lane + 64 * c == bi) sel[c] = true;
        if (lane == 0) {
            Aout[(b * Nn_ + i) * Nn_ + bi] = 1.0f;
            Aout[(b * Nn_ + bi) * Nn_ + i] = 1.0f;
        }
    }
    if (lane == 0) Aout[(b * Nn_ + i) * Nn_ + i] = 1.0f;
}

__global__ __launch_bounds__(256) void deg_k(const float* __restrict__ A, float* __restrict__ dinv)
{
    const int wid = threadIdx.x >> 6, lane = threadIdx.x & 63;
    const long row = (long)blockIdx.x * 4 + wid;
    const float* ar = A + row * Nn_;
    float s = 0.f;
    #pragma unroll
    for (int c = 0; c < 4; ++c) s += ar[lane + 64 * c];
    #pragma unroll
    for (int o = 32; o > 0; o >>= 1) s += __shfl_down(s, o);
    if (lane == 0) dinv[row] = rsqrtf(s);
}

// fused: Ahat bf16 = A*di*dj  AND  rsA[row] = rowsum(Ahat) in f32. One wave per row.
__global__ __launch_bounds__(256) void scalebf2_k(const float* __restrict__ A, const float* __restrict__ dinv,
                                                  u16* __restrict__ out, float* __restrict__ rsA)
{
    const int wid = threadIdx.x >> 6, lane = threadIdx.x & 63;
    const long row = (long)blockIdx.x * 4 + wid;
    const long b = row >> 8;
    const float di = dinv[row];
    const int j0 = lane * 4;
    const float4 dj = *(const float4*)&dinv[b * Nn_ + j0];
    const float4 a = *(const float4*)&A[row * Nn_ + j0];
    const float v0 = a.x * di * dj.x, v1 = a.y * di * dj.y, v2 = a.z * di * dj.z, v3 = a.w * di * dj.w;
    u16x4 o = { bfb(v0), bfb(v1), bfb(v2), bfb(v3) };
    *(u16x4*)&out[row * Nn_ + j0] = o;
    float s = v0 + v1 + v2 + v3;
    #pragma unroll
    for (int off = 32; off > 0; off >>= 1) s += __shfl_down(s, off);
    if (lane == 0) rsA[row] = s;
}

// mean-pool over nodes, bf16 input
__global__ __launch_bounds__(256) void poolb_k(const u16* __restrict__ y, float* __restrict__ pooled)
{
    const int d = blockIdx.x * 256 + threadIdx.x;
    const int b = blockIdx.y;
    const u16* yb = y + (long)b * Nn_ * Dd + d;
    float s = 0.f;
    #pragma unroll 4
    for (int n = 0; n < Nn_; ++n) s += fromb(yb[(long)n * Dd]);
    pooled[b * Dd + d] = s * (1.0f / Nn_);
}

// one wave per (batch, class) logit
__global__ __launch_bounds__(256) void cls2_k(const float* __restrict__ pooled, const float* __restrict__ WcT,
    const float* __restrict__ bc, float* __restrict__ out)
{
    const int w = threadIdx.x >> 6, lane = threadIdx.x & 63;
    const int c = blockIdx.x * 4 + w;
    const int b = blockIdx.y;
    const float* wr = WcT + (long)c * Dd;
    const float* p  = pooled + (long)b * Dd;
    float s = 0.f;
    #pragma unroll
    for (int it = 0; it < 4; ++it) {
        const float4 wv = *(const float4*)&wr[it * 256 + lane * 4];
        const float4 pv = *(const float4*)&p[it * 256 + lane * 4];
        s += wv.x * pv.x + wv.y * pv.y + wv.z * pv.z + wv.w * pv.w;
    }
    #pragma unroll
    for (int o = 32; o > 0; o >>= 1) s += __shfl_down(s, o);
    if (lane == 0) out[(long)b * NC + c] = s + bc[c];
}

extern "C" void kernel_launch(void* const* d_in, const int* in_sizes, int n_in,
                              void* d_out, int out_size, void* d_ws, size_t ws_size,
                              hipStream_t stream)
{
    const float* tokens = (const float*)d_in[0];
    const float* W1  = (const float*)d_in[1];
    const float* b1  = (const float*)d_in[2];
    const float* W2  = (const float*)d_in[3];
    const float* b2  = (const float*)d_in[4];
    const float* g1  = (const float*)d_in[5];
    const float* be1 = (const float*)d_in[6];
    const float* g2  = (const float*)d_in[7];
    const float* be2 = (const float*)d_in[8];
    const float* gr  = (const float*)d_in[9];
    const float* br  = (const float*)d_in[10];
    const float* Wc  = (const float*)d_in[11];
    const float* bc  = (const float*)d_in[12];
    const int*   kptr = (const int*)d_in[13];

    constexpr long SZ_XD = (long)Bb * Nn_ * Dd;   // 16.78M elems
    constexpr long SZ_A  = (long)Bb * Nn_ * Nn_;  //  4.19M elems

    // workspace carve (~155 MB; <= round-1-proven 218.5 MB)
    char* wp = (char*)d_ws;
    u16*   xbf    = (u16*)wp;   wp += SZ_XD * 2;   // residual trunk bf16 (kNN phase: AmatF f32)
    u16*   hbuf   = (u16*)wp;   wp += SZ_XD * 2;   // lin2' output h bf16 (kNN phase: d2f f32)
    u16*   bufA   = (u16*)wp;   wp += SZ_XD * 2;   // hilo lower | AZ | readout bf16
    u16*   bufB   = (u16*)wp;   wp += SZ_XD * 2;   // hilo upper (kNN only)
    u16*   bufC   = (u16*)wp;   wp += SZ_XD * 2;   // LN1 output bf16 (ayy2 A-operand)
    u16*   AmatBF = (u16*)wp;   wp += SZ_A * 2;
    u16*   W1t    = (u16*)wp;   wp += 2L * Dd * Hh * 2;
    u16*   W2t    = (u16*)wp;   wp += 2L * Hh * Dd * 2;
    float* WcT    = (float*)wp; wp += (long)NC * Dd * 4;
    float* sq     = (float*)wp; wp += (long)Bb * Nn_ * 4;
    float* dinv   = (float*)wp; wp += (long)Bb * Nn_ * 4;
    float* rsA    = (float*)wp; wp += (long)Bb * Nn_ * 4;
    float* pooled = (float*)wp; wp += (long)Bb * Dd * 4;

    // phase aliases (lifetimes disjoint):
    u16*   hilo  = bufA;            // [B*N][2048] bf16 hi|lo spans bufA+bufB, dead after d2mm
    float* d2f   = (float*)hbuf;    // f32 distances, dead after topk; h first written iter0 lin2'
    float* AmatF = (float*)xbf;     // f32 adjacency, dead after scalebf2; x first written iter0 ln2fr
    u16*   robuf = bufA;            // readout bf16 (AZ dead after lin2' of last iter)

    const dim3 blk(256);
    const dim3 blk8(512);

    // ---- fused prep (wave-per-row): tokens -> hilo + sq + LN1(block0) in ONE pass ----
    prep_k<<<Bb * Nn_ / 4, blk, 0, stream>>>(tokens, hilo, sq, bufC, g1, be1);

    // ---- kNN adjacency: triangle + XCD-swizzled d2, 8-wave blocks ----
    d2mm_k<<<192, blk8, 0, stream>>>(hilo, sq, d2f);
    clear_k<<<(int)(SZ_A / 4 / 256), blk, 0, stream>>>((float4*)AmatF);
    topk_k<<<Bb * Nn_ / 4, blk, 0, stream>>>(d2f, AmatF, kptr);
    deg_k<<<Bb * Nn_ / 4, blk, 0, stream>>>(AmatF, dinv);
    scalebf2_k<<<Bb * Nn_ / 4, blk, 0, stream>>>(AmatF, dinv, AmatBF, rsA);

    // ---- weight transposes ----
    transw_k<<<dim3(Hh / 32, Dd / 32, 2), blk, 0, stream>>>(W1, W1t, Dd, Hh, (long)Dd * Hh, (long)Hh * Dd);
    transw_k<<<dim3(Dd / 32, Hh / 32, 2), blk, 0, stream>>>(W2, W2t, Hh, Dd, (long)Hh * Dd, (long)Dd * Hh);
    transc_k<<<dim3(32, Dd / 32), blk, 0, stream>>>(Wc, WcT);

    // ---- GraphBlocks ----
    for (int i = 0; i < 2; ++i) {
        // fused lin1 + AY double-multiply: AZ = Ahat @ gelu(Ahat @ (LN1@W1+b1))   (256 blocks)
        ayy2_k<<<256, blk8, 0, stream>>>(AmatBF, bufC, W1t + (long)i * Hh * Dd, b1 + (long)i * Hh, bufA);
        // lin2': h[16384][1024] = AZ @ W2 + rsA*b2   (nx=8, ny=128, nz=1 -> 1024 blocks)
        mgemm_k<EP_SBIAS_BF><<<1024, blk8, 0, stream>>>(
            bufA, W2t + (long)i * Dd * Hh, hbuf, b2 + i * Dd, rsA,
            Bb * Nn_, Dd, Hh, 0, 0, 0, 3, 7, 0);
        // fused residual + double-LN (wave-per-row)
        if (i == 0)
            ln2fr_k<0, 1><<<Bb * Nn_ / 4, blk, 0, stream>>>(hbuf, tokens, xbf, bufC,
                g2, be2, g1 + Dd, be1 + Dd);
        else
            ln2fr_k<1, 0><<<Bb * Nn_ / 4, blk, 0, stream>>>(hbuf, xbf, nullptr, robuf,
                g2 + Dd, be2 + Dd, gr, br);
    }

    // ---- pool + classifier ----
    poolb_k<<<dim3(Dd / 256, Bb), blk, 0, stream>>>(robuf, pooled);
    cls2_k<<<dim3(NC / 4, Bb), blk, 0, stream>>>(pooled, WcT, bc, (float*)d_out);
}